// Round 8
// baseline (261.989 us; speedup 1.0000x reference)
//
#include <hip/hip_runtime.h>
#include <hip/hip_fp16.h>
#include <math.h>

#define DCONV 16
#define BSH 8            // nodes per bucket = 256
#define GPART 512        // partition blocks (parallelism for hist/scatter)
#define MAXNB 512

// ---------------- bucketed CSR build ----------------

__global__ void k_hist(const int* __restrict__ ei, int E, int nb_buckets, int chunk,
                       int* __restrict__ cnt) {
  __shared__ int hist[MAXNB];
  int g = blockIdx.x;
  for (int i = threadIdx.x; i < nb_buckets; i += 256) hist[i] = 0;
  __syncthreads();
  int e0 = g * chunk, e1 = min(e0 + chunk, E);
  for (int e = e0 + threadIdx.x; e < e1; e += 256)
    atomicAdd(&hist[ei[E + e] >> BSH], 1);
  __syncthreads();
  for (int i = threadIdx.x; i < nb_buckets; i += 256)
    cnt[i * GPART + g] = hist[i];
}

__global__ void k_block_sums(const int* __restrict__ in, int n, int* __restrict__ part) {
  int i = blockIdx.x * 256 + threadIdx.x;
  int v = (i < n) ? in[i] : 0;
  #pragma unroll
  for (int off = 32; off > 0; off >>= 1) v += __shfl_down(v, off, 64);
  __shared__ int ws[4];
  if ((threadIdx.x & 63) == 0) ws[threadIdx.x >> 6] = v;
  __syncthreads();
  if (threadIdx.x == 0) part[blockIdx.x] = ws[0] + ws[1] + ws[2] + ws[3];
}

// single block, 1024 threads; nb <= 1024
__global__ void k_scan_part(int* __restrict__ part, int nb) {
  __shared__ int s[1024];
  int t = threadIdx.x;
  int v = (t < nb) ? part[t] : 0;
  s[t] = v;
  __syncthreads();
  for (int off = 1; off < 1024; off <<= 1) {
    int u = (t >= off) ? s[t - off] : 0;
    __syncthreads();
    s[t] += u;
    __syncthreads();
  }
  if (t < nb) part[t] = s[t] - v;  // exclusive prefix
}

__global__ void k_excl_apply(const int* __restrict__ in, int n, const int* __restrict__ part,
                             int* __restrict__ out) {
  __shared__ int s[256];
  int t = threadIdx.x;
  int i = blockIdx.x * 256 + t;
  int v = (i < n) ? in[i] : 0;
  s[t] = v;
  __syncthreads();
  for (int off = 1; off < 256; off <<= 1) {
    int u = (t >= off) ? s[t - off] : 0;
    __syncthreads();
    s[t] += u;
    __syncthreads();
  }
  if (i < n) out[i] = s[t] - v + part[blockIdx.x];
}

__global__ void k_scatter(const int* __restrict__ ei, int E, int nb_buckets, int chunk,
                          const int* __restrict__ off, int* __restrict__ temp) {
  __shared__ int cur[MAXNB];
  int g = blockIdx.x;
  for (int i = threadIdx.x; i < nb_buckets; i += 256) cur[i] = off[i * GPART + g];
  __syncthreads();
  int e0 = g * chunk, e1 = min(e0 + chunk, E);
  for (int e = e0 + threadIdx.x; e < e1; e += 256) {
    int s = ei[e];
    int d = ei[E + e];
    int b = d >> BSH;
    int pos = atomicAdd(&cur[b], 1);
    temp[pos] = (s << BSH) | (d & ((1 << BSH) - 1));
  }
}

__global__ void k_fine(const int* __restrict__ temp, const int* __restrict__ off,
                       int nb_buckets, int E, int n,
                       int* __restrict__ rowptr, int* __restrict__ csr) {
  __shared__ int hist[1 << BSH];
  __shared__ int cur[1 << BSH];
  int b = blockIdx.x, t = threadIdx.x;
  int lo = off[b * GPART];
  int hi = (b == nb_buckets - 1) ? E : off[(b + 1) * GPART];
  hist[t] = 0;
  __syncthreads();
  for (int e = lo + t; e < hi; e += 256)
    atomicAdd(&hist[temp[e] & 255], 1);
  __syncthreads();
  int v = hist[t];
  cur[t] = v;
  __syncthreads();
  for (int offm = 1; offm < 256; offm <<= 1) {
    int u = (t >= offm) ? cur[t - offm] : 0;
    __syncthreads();
    cur[t] += u;
    __syncthreads();
  }
  int excl = cur[t] - v;
  int node = (b << BSH) + t;
  if (node < n) rowptr[node] = lo + excl;
  if (b == nb_buckets - 1 && t == 0) rowptr[n] = hi;
  cur[t] = lo + excl;
  __syncthreads();
  for (int e = lo + t; e < hi; e += 256) {
    int p = temp[e];
    int pos = atomicAdd(&cur[p & 255], 1);
    csr[pos] = p >> BSH;
  }
}

// ---------------- pre-transform: y = fp16(h @ Wl) ----------------

__global__ void k_xform32h(const float* __restrict__ xin,
                           const float* __restrict__ Wl,
                           __half* __restrict__ y, int n) {
  __shared__ float sWl[32 * 16];
  int t = threadIdx.x;
  for (int i = t; i < 32 * 16; i += 256) sWl[i] = Wl[i];
  __syncthreads();
  int l = t & 15;
  int base = (t & 63) & ~15;
  int node = (blockIdx.x * 256 + t) >> 4;
  if (node >= n) return;
  float x0 = xin[node * 32 + l];
  float x1 = xin[node * 32 + 16 + l];
  float ay = 0.f;
  #pragma unroll
  for (int i = 0; i < 16; ++i) {
    float v0 = __shfl(x0, base + i, 64);
    float v1 = __shfl(x1, base + i, 64);
    ay += v0 * sWl[i * 16 + l] + v1 * sWl[(16 + i) * 16 + l];
  }
  y[node * 16 + l] = __float2half_rn(ay);
}

__global__ void k_xform16h(const float* __restrict__ hin,
                           const float* __restrict__ Wl,
                           __half* __restrict__ y, int n) {
  __shared__ float sWl[16 * 16];
  int t = threadIdx.x;
  for (int i = t; i < 16 * 16; i += 256) sWl[i] = Wl[i];
  __syncthreads();
  int l = t & 15;
  int base = (t & 63) & ~15;
  int node = (blockIdx.x * 256 + t) >> 4;
  if (node >= n) return;
  float x0 = hin[node * 16 + l];
  float ay = 0.f;
  #pragma unroll
  for (int i = 0; i < 16; ++i) {
    float v0 = __shfl(x0, base + i, 64);
    ay += v0 * sWl[i * 16 + l];
  }
  y[node * 16 + l] = __float2half_rn(ay);
}

// ---------------- aggregate: out = elu(mean_gather(y16) + h@Wr + b) ----------------

template <int DI>
__global__ void k_agg(const __half* __restrict__ y, const float* __restrict__ hin,
                      const float* __restrict__ Wr, const float* __restrict__ bias,
                      const int* __restrict__ rowptr, const int* __restrict__ csr,
                      float* __restrict__ outp, int n) {
  __shared__ __align__(16) float sWr[DI * 16];
  __shared__ float sb[16];
  {
    int tt = threadIdx.x;
    for (int i = tt; i < DI * 16; i += 256) sWr[i] = Wr[i];
    if (tt < 16) sb[tt] = bias[tt];
  }
  __syncthreads();

  int t = blockIdx.x * 256 + threadIdx.x;
  int l = t & 3;
  int node = t >> 2;
  if (node >= n) return;
  int r0 = rowptr[node], r1 = rowptr[node + 1];

  const uint2* __restrict__ yv = reinterpret_cast<const uint2*>(y);

  float a0 = 0.f, a1 = 0.f, a2 = 0.f, a3 = 0.f;
  float b0 = 0.f, b1 = 0.f, b2 = 0.f, b3 = 0.f;
  float c0 = 0.f, c1 = 0.f, c2 = 0.f, c3 = 0.f;
  float d0 = 0.f, d1 = 0.f, d2 = 0.f, d3 = 0.f;
  int k = r0;
  for (; k + 3 < r1; k += 4) {
    int ia = csr[k], ib = csr[k + 1], ic = csr[k + 2], id = csr[k + 3];
    uint2 ra = yv[ia * 4 + l];
    uint2 rb = yv[ib * 4 + l];
    uint2 rc = yv[ic * 4 + l];
    uint2 rd = yv[id * 4 + l];
    float2 fa0 = __half22float2(*reinterpret_cast<const __half2*>(&ra.x));
    float2 fa1 = __half22float2(*reinterpret_cast<const __half2*>(&ra.y));
    float2 fb0 = __half22float2(*reinterpret_cast<const __half2*>(&rb.x));
    float2 fb1 = __half22float2(*reinterpret_cast<const __half2*>(&rb.y));
    float2 fc0 = __half22float2(*reinterpret_cast<const __half2*>(&rc.x));
    float2 fc1 = __half22float2(*reinterpret_cast<const __half2*>(&rc.y));
    float2 fd0 = __half22float2(*reinterpret_cast<const __half2*>(&rd.x));
    float2 fd1 = __half22float2(*reinterpret_cast<const __half2*>(&rd.y));
    a0 += fa0.x; a1 += fa0.y; a2 += fa1.x; a3 += fa1.y;
    b0 += fb0.x; b1 += fb0.y; b2 += fb1.x; b3 += fb1.y;
    c0 += fc0.x; c1 += fc0.y; c2 += fc1.x; c3 += fc1.y;
    d0 += fd0.x; d1 += fd0.y; d2 += fd1.x; d3 += fd1.y;
  }
  for (; k < r1; ++k) {
    int ia = csr[k];
    uint2 ra = yv[ia * 4 + l];
    float2 fa0 = __half22float2(*reinterpret_cast<const __half2*>(&ra.x));
    float2 fa1 = __half22float2(*reinterpret_cast<const __half2*>(&ra.y));
    a0 += fa0.x; a1 += fa0.y; a2 += fa1.x; a3 += fa1.y;
  }
  float s0 = a0 + b0 + c0 + d0;
  float s1 = a1 + b1 + c1 + d1;
  float s2 = a2 + b2 + c2 + d2;
  float s3 = a3 + b3 + c3 + d3;
  float inv = 1.f / fmaxf((float)(r1 - r0), 1.f);

  int cbase = l * 4;
  float4 rr = *reinterpret_cast<const float4*>(&sb[cbase]);
  #pragma unroll
  for (int i = 0; i < DI; ++i) {
    float h = hin[node * DI + i];
    float4 w = *reinterpret_cast<const float4*>(&sWr[i * 16 + cbase]);
    rr.x += h * w.x; rr.y += h * w.y; rr.z += h * w.z; rr.w += h * w.w;
  }

  float ax = s0 * inv + rr.x;
  float ay = s1 * inv + rr.y;
  float az = s2 * inv + rr.z;
  float aw = s3 * inv + rr.w;
  float4 o;
  o.x = ax > 0.f ? ax : (__expf(ax) - 1.f);
  o.y = ay > 0.f ? ay : (__expf(ay) - 1.f);
  o.z = az > 0.f ? az : (__expf(az) - 1.f);
  o.w = aw > 0.f ? aw : (__expf(aw) - 1.f);
  *reinterpret_cast<float4*>(&outp[node * 16 + cbase]) = o;
}

// ---------------- fused 4-layer MLP (16 lanes/group, 8 nodes/group) ----------------
// Weights from global (L1-resident), amortized over 8 nodes/group. Activations
// in LDS rows (broadcast reads within the group, intra-wave -> barrier-free).

#define HSTRIDE 68

__device__ __forceinline__ float4 elu4(float4 a) {
  float4 r;
  r.x = a.x > 0.f ? a.x : (__expf(a.x) - 1.f);
  r.y = a.y > 0.f ? a.y : (__expf(a.y) - 1.f);
  r.z = a.z > 0.f ? a.z : (__expf(a.z) - 1.f);
  r.w = a.w > 0.f ? a.w : (__expf(a.w) - 1.f);
  return r;
}

__device__ __forceinline__ void fma16(float4& a, const float4 h,
                                      const float4 w0, const float4 w1,
                                      const float4 w2, const float4 w3) {
  a.x += h.x * w0.x + h.y * w1.x + h.z * w2.x + h.w * w3.x;
  a.y += h.x * w0.y + h.y * w1.y + h.z * w2.y + h.w * w3.y;
  a.z += h.x * w0.z + h.y * w1.z + h.z * w2.z + h.w * w3.z;
  a.w += h.x * w0.w + h.y * w1.w + h.z * w2.w + h.w * w3.w;
}

__global__ void __launch_bounds__(256) k_mlp(
    const float* __restrict__ xin,
    const float* __restrict__ W0, const float* __restrict__ B0,
    const float* __restrict__ W1, const float* __restrict__ B1,
    const float* __restrict__ W2, const float* __restrict__ B2,
    const float* __restrict__ W3, const float* __restrict__ B3,
    float* __restrict__ out, int n) {
  __shared__ __align__(16) float hrow[128 * HSTRIDE];  // 16 groups * 8 rows
  __shared__ __align__(16) float sW3T[4 * 64];         // W3 transposed: [c][i]
  int t = threadIdx.x;
  int l = t & 15;
  int gb = t >> 4;
  int group = blockIdx.x * 16 + gb;
  int nodeBase = group * 8;
  bool active = nodeBase < n;
  int row0 = gb * 8;

  sW3T[(t & 3) * 64 + (t >> 2)] = W3[t];

  // stage 8 nodes * 16 floats = 32 float4; lane l covers float4 #l and #(l+16)
  if (active) {
    #pragma unroll
    for (int p = 0; p < 2; ++p) {
      int f = l + p * 16;
      int nd = f >> 2;
      float4 v = make_float4(0.f, 0.f, 0.f, 0.f);
      if (nodeBase + nd < n)
        v = *reinterpret_cast<const float4*>(&xin[nodeBase * 16 + f * 4]);
      *reinterpret_cast<float4*>(&hrow[(row0 + nd) * HSTRIDE + (f & 3) * 4]) = v;
    }
  }
  __syncthreads();

  if (active) {
    float4 ac0, ac1, ac2, ac3, ac4, ac5, ac6, ac7;

    // ---- layer0: 16 -> 64 ----
    ac0 = *reinterpret_cast<const float4*>(&B0[4 * l]);
    ac1 = ac0; ac2 = ac0; ac3 = ac0; ac4 = ac0; ac5 = ac0; ac6 = ac0; ac7 = ac0;
    #pragma unroll
    for (int j = 0; j < 4; ++j) {
      float4 w0 = *reinterpret_cast<const float4*>(&W0[(4 * j + 0) * 64 + 4 * l]);
      float4 w1 = *reinterpret_cast<const float4*>(&W0[(4 * j + 1) * 64 + 4 * l]);
      float4 w2 = *reinterpret_cast<const float4*>(&W0[(4 * j + 2) * 64 + 4 * l]);
      float4 w3 = *reinterpret_cast<const float4*>(&W0[(4 * j + 3) * 64 + 4 * l]);
      fma16(ac0, *reinterpret_cast<const float4*>(&hrow[(row0 + 0) * HSTRIDE + j * 4]), w0, w1, w2, w3);
      fma16(ac1, *reinterpret_cast<const float4*>(&hrow[(row0 + 1) * HSTRIDE + j * 4]), w0, w1, w2, w3);
      fma16(ac2, *reinterpret_cast<const float4*>(&hrow[(row0 + 2) * HSTRIDE + j * 4]), w0, w1, w2, w3);
      fma16(ac3, *reinterpret_cast<const float4*>(&hrow[(row0 + 3) * HSTRIDE + j * 4]), w0, w1, w2, w3);
      fma16(ac4, *reinterpret_cast<const float4*>(&hrow[(row0 + 4) * HSTRIDE + j * 4]), w0, w1, w2, w3);
      fma16(ac5, *reinterpret_cast<const float4*>(&hrow[(row0 + 5) * HSTRIDE + j * 4]), w0, w1, w2, w3);
      fma16(ac6, *reinterpret_cast<const float4*>(&hrow[(row0 + 6) * HSTRIDE + j * 4]), w0, w1, w2, w3);
      fma16(ac7, *reinterpret_cast<const float4*>(&hrow[(row0 + 7) * HSTRIDE + j * 4]), w0, w1, w2, w3);
    }
    *reinterpret_cast<float4*>(&hrow[(row0 + 0) * HSTRIDE + l * 4]) = elu4(ac0);
    *reinterpret_cast<float4*>(&hrow[(row0 + 1) * HSTRIDE + l * 4]) = elu4(ac1);
    *reinterpret_cast<float4*>(&hrow[(row0 + 2) * HSTRIDE + l * 4]) = elu4(ac2);
    *reinterpret_cast<float4*>(&hrow[(row0 + 3) * HSTRIDE + l * 4]) = elu4(ac3);
    *reinterpret_cast<float4*>(&hrow[(row0 + 4) * HSTRIDE + l * 4]) = elu4(ac4);
    *reinterpret_cast<float4*>(&hrow[(row0 + 5) * HSTRIDE + l * 4]) = elu4(ac5);
    *reinterpret_cast<float4*>(&hrow[(row0 + 6) * HSTRIDE + l * 4]) = elu4(ac6);
    *reinterpret_cast<float4*>(&hrow[(row0 + 7) * HSTRIDE + l * 4]) = elu4(ac7);

    // ---- layers 1 & 2: 64 -> 64 ----
    const float* Ws[2] = {W1, W2};
    const float* Bs[2] = {B1, B2};
    #pragma unroll
    for (int layer = 0; layer < 2; ++layer) {
      const float* __restrict__ W = Ws[layer];
      ac0 = *reinterpret_cast<const float4*>(&Bs[layer][4 * l]);
      ac1 = ac0; ac2 = ac0; ac3 = ac0; ac4 = ac0; ac5 = ac0; ac6 = ac0; ac7 = ac0;
      #pragma unroll 2
      for (int j = 0; j < 16; ++j) {
        float4 w0 = *reinterpret_cast<const float4*>(&W[(4 * j + 0) * 64 + 4 * l]);
        float4 w1 = *reinterpret_cast<const float4*>(&W[(4 * j + 1) * 64 + 4 * l]);
        float4 w2 = *reinterpret_cast<const float4*>(&W[(4 * j + 2) * 64 + 4 * l]);
        float4 w3 = *reinterpret_cast<const float4*>(&W[(4 * j + 3) * 64 + 4 * l]);
        fma16(ac0, *reinterpret_cast<const float4*>(&hrow[(row0 + 0) * HSTRIDE + j * 4]), w0, w1, w2, w3);
        fma16(ac1, *reinterpret_cast<const float4*>(&hrow[(row0 + 1) * HSTRIDE + j * 4]), w0, w1, w2, w3);
        fma16(ac2, *reinterpret_cast<const float4*>(&hrow[(row0 + 2) * HSTRIDE + j * 4]), w0, w1, w2, w3);
        fma16(ac3, *reinterpret_cast<const float4*>(&hrow[(row0 + 3) * HSTRIDE + j * 4]), w0, w1, w2, w3);
        fma16(ac4, *reinterpret_cast<const float4*>(&hrow[(row0 + 4) * HSTRIDE + j * 4]), w0, w1, w2, w3);
        fma16(ac5, *reinterpret_cast<const float4*>(&hrow[(row0 + 5) * HSTRIDE + j * 4]), w0, w1, w2, w3);
        fma16(ac6, *reinterpret_cast<const float4*>(&hrow[(row0 + 6) * HSTRIDE + j * 4]), w0, w1, w2, w3);
        fma16(ac7, *reinterpret_cast<const float4*>(&hrow[(row0 + 7) * HSTRIDE + j * 4]), w0, w1, w2, w3);
      }
      *reinterpret_cast<float4*>(&hrow[(row0 + 0) * HSTRIDE + l * 4]) = elu4(ac0);
      *reinterpret_cast<float4*>(&hrow[(row0 + 1) * HSTRIDE + l * 4]) = elu4(ac1);
      *reinterpret_cast<float4*>(&hrow[(row0 + 2) * HSTRIDE + l * 4]) = elu4(ac2);
      *reinterpret_cast<float4*>(&hrow[(row0 + 3) * HSTRIDE + l * 4]) = elu4(ac3);
      *reinterpret_cast<float4*>(&hrow[(row0 + 4) * HSTRIDE + l * 4]) = elu4(ac4);
      *reinterpret_cast<float4*>(&hrow[(row0 + 5) * HSTRIDE + l * 4]) = elu4(ac5);
      *reinterpret_cast<float4*>(&hrow[(row0 + 6) * HSTRIDE + l * 4]) = elu4(ac6);
      *reinterpret_cast<float4*>(&hrow[(row0 + 7) * HSTRIDE + l * 4]) = elu4(ac7);
    }

    // ---- layer3: 64 -> 4; lane l covers (node l>>2, ch l&3) and (node (l>>2)+4, same ch)
    {
      int nd = l >> 2, c = l & 3;
      float accA = B3[c], accB = B3[c];
      #pragma unroll 4
      for (int i = 0; i < 16; ++i) {
        float4 w = *reinterpret_cast<const float4*>(&sW3T[c * 64 + i * 4]);
        float4 ha = *reinterpret_cast<const float4*>(&hrow[(row0 + nd) * HSTRIDE + i * 4]);
        float4 hb = *reinterpret_cast<const float4*>(&hrow[(row0 + nd + 4) * HSTRIDE + i * 4]);
        accA += ha.x * w.x + ha.y * w.y + ha.z * w.z + ha.w * w.w;
        accB += hb.x * w.x + hb.y * w.y + hb.z * w.z + hb.w * w.w;
      }
      if (nodeBase + nd < n) out[(nodeBase + nd) * 4 + c] = accA;
      if (nodeBase + nd + 4 < n) out[(nodeBase + nd + 4) * 4 + c] = accB;
    }
  }
}

// ---------------- launch ----------------

extern "C" void kernel_launch(void* const* d_in, const int* in_sizes, int n_in,
                              void* d_out, int out_size, void* d_ws, size_t ws_size,
                              hipStream_t stream) {
  const float* x   = (const float*)d_in[0];
  const int*   ei  = (const int*)d_in[1];
  const float* Wl0 = (const float*)d_in[2];
  const float* Wr0 = (const float*)d_in[3];
  const float* bl0 = (const float*)d_in[4];
  const float* Wl1 = (const float*)d_in[5];
  const float* Wr1 = (const float*)d_in[6];
  const float* bl1 = (const float*)d_in[7];
  const float* Wl2 = (const float*)d_in[8];
  const float* Wr2 = (const float*)d_in[9];
  const float* bl2 = (const float*)d_in[10];
  const float* LW0 = (const float*)d_in[11];
  const float* LB0 = (const float*)d_in[12];
  const float* LW1 = (const float*)d_in[13];
  const float* LB1 = (const float*)d_in[14];
  const float* LW2 = (const float*)d_in[15];
  const float* LB2 = (const float*)d_in[16];
  const float* LW3 = (const float*)d_in[17];
  const float* LB3 = (const float*)d_in[18];
  float* out = (float*)d_out;

  const int N_ = in_sizes[0] / 32;   // 100000
  const int E_ = in_sizes[1] / 2;    // 3200000

  const int NB = (N_ + (1 << BSH) - 1) >> BSH;        // 391 buckets
  const int chunk = (E_ + GPART - 1) / GPART;
  const int n2 = NB * GPART;                           // 200192
  const int nb2 = (n2 + 255) / 256;                    // 782 <= 1024

  char* wsp = (char*)d_ws;
  int* cnt    = (int*)wsp;  wsp += sizeof(int) * (size_t)n2;
  int* off    = (int*)wsp;  wsp += sizeof(int) * (size_t)n2;
  int* part   = (int*)wsp;  wsp += sizeof(int) * 1024;
  int* temp   = (int*)wsp;  wsp += sizeof(int) * (size_t)E_;   // 12.8 MB, dead after k_fine
  int* csr    = (int*)wsp;  wsp += sizeof(int) * (size_t)E_;
  size_t hBytes = sizeof(float) * (size_t)N_ * DCONV;          // 6.4 MB
  float* Ha   = (float*)wsp; wsp += hBytes;
  int* rowptr = (int*)wsp;  wsp += sizeof(int) * (size_t)(N_ + 1);
  // reuse temp: y16 (3.2 MB) + Hb (6.4 MB) <= 12.8 MB
  __half* y16 = (__half*)temp;
  float*  Hb  = (float*)((char*)temp + sizeof(__half) * (size_t)N_ * DCONV);

  // CSR build
  k_hist<<<GPART, 256, 0, stream>>>(ei, E_, NB, chunk, cnt);
  k_block_sums<<<nb2, 256, 0, stream>>>(cnt, n2, part);
  k_scan_part<<<1, 1024, 0, stream>>>(part, nb2);
  k_excl_apply<<<nb2, 256, 0, stream>>>(cnt, n2, part, off);
  k_scatter<<<GPART, 256, 0, stream>>>(ei, E_, NB, chunk, off, temp);
  k_fine<<<NB, 256, 0, stream>>>(temp, off, NB, E_, N_, rowptr, csr);

  int nbX = (N_ * 16 + 255) / 256;   // xform grids
  int nbA = (N_ * 4 + 255) / 256;    // agg grids

  // conv0: x -> Ha
  k_xform32h<<<nbX, 256, 0, stream>>>(x, Wl0, y16, N_);
  k_agg<32><<<nbA, 256, 0, stream>>>(y16, x, Wr0, bl0, rowptr, csr, Ha, N_);
  // conv1: Ha -> Hb
  k_xform16h<<<nbX, 256, 0, stream>>>(Ha, Wl1, y16, N_);
  k_agg<16><<<nbA, 256, 0, stream>>>(y16, Ha, Wr1, bl1, rowptr, csr, Hb, N_);
  // conv2: Hb -> Ha
  k_xform16h<<<nbX, 256, 0, stream>>>(Hb, Wl2, y16, N_);
  k_agg<16><<<nbA, 256, 0, stream>>>(y16, Hb, Wr2, bl2, rowptr, csr, Ha, N_);

  // MLP: 16 lanes per group, 8 nodes per group
  int groups = (N_ + 7) / 8;
  int nbM = (groups + 15) / 16;
  k_mlp<<<nbM, 256, 0, stream>>>(Ha, LW0, LB0, LW1, LB1, LW2, LB2, LW3, LB3, out, N_);
}

// Round 9
// 253.468 us; speedup vs baseline: 1.0336x; 1.0336x over previous
//
#include <hip/hip_runtime.h>
#include <hip/hip_fp16.h>
#include <math.h>

#define DCONV 16
#define BSH 8            // nodes per bucket = 256
#define GPART 512        // partition blocks (parallelism for hist/scatter)
#define MAXNB 512

// ---------------- bucketed CSR build ----------------

__global__ void k_hist(const int* __restrict__ ei, int E, int nb_buckets, int chunk,
                       int* __restrict__ cnt) {
  __shared__ int hist[MAXNB];
  int g = blockIdx.x;
  for (int i = threadIdx.x; i < nb_buckets; i += 256) hist[i] = 0;
  __syncthreads();
  int e0 = g * chunk, e1 = min(e0 + chunk, E);
  for (int e = e0 + threadIdx.x; e < e1; e += 256)
    atomicAdd(&hist[ei[E + e] >> BSH], 1);
  __syncthreads();
  for (int i = threadIdx.x; i < nb_buckets; i += 256)
    cnt[i * GPART + g] = hist[i];
}

__global__ void k_block_sums(const int* __restrict__ in, int n, int* __restrict__ part) {
  int i = blockIdx.x * 256 + threadIdx.x;
  int v = (i < n) ? in[i] : 0;
  #pragma unroll
  for (int off = 32; off > 0; off >>= 1) v += __shfl_down(v, off, 64);
  __shared__ int ws[4];
  if ((threadIdx.x & 63) == 0) ws[threadIdx.x >> 6] = v;
  __syncthreads();
  if (threadIdx.x == 0) part[blockIdx.x] = ws[0] + ws[1] + ws[2] + ws[3];
}

// single block, 1024 threads; nb <= 1024
__global__ void k_scan_part(int* __restrict__ part, int nb) {
  __shared__ int s[1024];
  int t = threadIdx.x;
  int v = (t < nb) ? part[t] : 0;
  s[t] = v;
  __syncthreads();
  for (int off = 1; off < 1024; off <<= 1) {
    int u = (t >= off) ? s[t - off] : 0;
    __syncthreads();
    s[t] += u;
    __syncthreads();
  }
  if (t < nb) part[t] = s[t] - v;  // exclusive prefix
}

__global__ void k_excl_apply(const int* __restrict__ in, int n, const int* __restrict__ part,
                             int* __restrict__ out) {
  __shared__ int s[256];
  int t = threadIdx.x;
  int i = blockIdx.x * 256 + t;
  int v = (i < n) ? in[i] : 0;
  s[t] = v;
  __syncthreads();
  for (int off = 1; off < 256; off <<= 1) {
    int u = (t >= off) ? s[t - off] : 0;
    __syncthreads();
    s[t] += u;
    __syncthreads();
  }
  if (i < n) out[i] = s[t] - v + part[blockIdx.x];
}

__global__ void k_scatter(const int* __restrict__ ei, int E, int nb_buckets, int chunk,
                          const int* __restrict__ off, int* __restrict__ temp) {
  __shared__ int cur[MAXNB];
  int g = blockIdx.x;
  for (int i = threadIdx.x; i < nb_buckets; i += 256) cur[i] = off[i * GPART + g];
  __syncthreads();
  int e0 = g * chunk, e1 = min(e0 + chunk, E);
  for (int e = e0 + threadIdx.x; e < e1; e += 256) {
    int s = ei[e];
    int d = ei[E + e];
    int b = d >> BSH;
    int pos = atomicAdd(&cur[b], 1);
    temp[pos] = (s << BSH) | (d & ((1 << BSH) - 1));
  }
}

__global__ void k_fine(const int* __restrict__ temp, const int* __restrict__ off,
                       int nb_buckets, int E, int n,
                       int* __restrict__ rowptr, int* __restrict__ csr) {
  __shared__ int hist[1 << BSH];
  __shared__ int cur[1 << BSH];
  int b = blockIdx.x, t = threadIdx.x;
  int lo = off[b * GPART];
  int hi = (b == nb_buckets - 1) ? E : off[(b + 1) * GPART];
  hist[t] = 0;
  __syncthreads();
  for (int e = lo + t; e < hi; e += 256)
    atomicAdd(&hist[temp[e] & 255], 1);
  __syncthreads();
  int v = hist[t];
  cur[t] = v;
  __syncthreads();
  for (int offm = 1; offm < 256; offm <<= 1) {
    int u = (t >= offm) ? cur[t - offm] : 0;
    __syncthreads();
    cur[t] += u;
    __syncthreads();
  }
  int excl = cur[t] - v;
  int node = (b << BSH) + t;
  if (node < n) rowptr[node] = lo + excl;
  if (b == nb_buckets - 1 && t == 0) rowptr[n] = hi;
  cur[t] = lo + excl;
  __syncthreads();
  for (int e = lo + t; e < hi; e += 256) {
    int p = temp[e];
    int pos = atomicAdd(&cur[p & 255], 1);
    csr[pos] = p >> BSH;
  }
}

// ---------------- pre-transform: y = fp16(h @ Wl) ----------------

__global__ void k_xform32h(const float* __restrict__ xin,
                           const float* __restrict__ Wl,
                           __half* __restrict__ y, int n) {
  __shared__ float sWl[32 * 16];
  int t = threadIdx.x;
  for (int i = t; i < 32 * 16; i += 256) sWl[i] = Wl[i];
  __syncthreads();
  int l = t & 15;
  int base = (t & 63) & ~15;
  int node = (blockIdx.x * 256 + t) >> 4;
  if (node >= n) return;
  float x0 = xin[node * 32 + l];
  float x1 = xin[node * 32 + 16 + l];
  float ay = 0.f;
  #pragma unroll
  for (int i = 0; i < 16; ++i) {
    float v0 = __shfl(x0, base + i, 64);
    float v1 = __shfl(x1, base + i, 64);
    ay += v0 * sWl[i * 16 + l] + v1 * sWl[(16 + i) * 16 + l];
  }
  y[node * 16 + l] = __float2half_rn(ay);
}

__global__ void k_xform16h(const float* __restrict__ hin,
                           const float* __restrict__ Wl,
                           __half* __restrict__ y, int n) {
  __shared__ float sWl[16 * 16];
  int t = threadIdx.x;
  for (int i = t; i < 16 * 16; i += 256) sWl[i] = Wl[i];
  __syncthreads();
  int l = t & 15;
  int base = (t & 63) & ~15;
  int node = (blockIdx.x * 256 + t) >> 4;
  if (node >= n) return;
  float x0 = hin[node * 16 + l];
  float ay = 0.f;
  #pragma unroll
  for (int i = 0; i < 16; ++i) {
    float v0 = __shfl(x0, base + i, 64);
    ay += v0 * sWl[i * 16 + l];
  }
  y[node * 16 + l] = __float2half_rn(ay);
}

// ---------------- aggregate: out = elu(mean_gather(y16) + h@Wr + b) ----------------

template <int DI>
__global__ void k_agg(const __half* __restrict__ y, const float* __restrict__ hin,
                      const float* __restrict__ Wr, const float* __restrict__ bias,
                      const int* __restrict__ rowptr, const int* __restrict__ csr,
                      float* __restrict__ outp, int n) {
  __shared__ __align__(16) float sWr[DI * 16];
  __shared__ float sb[16];
  {
    int tt = threadIdx.x;
    for (int i = tt; i < DI * 16; i += 256) sWr[i] = Wr[i];
    if (tt < 16) sb[tt] = bias[tt];
  }
  __syncthreads();

  int t = blockIdx.x * 256 + threadIdx.x;
  int l = t & 3;
  int node = t >> 2;
  if (node >= n) return;
  int r0 = rowptr[node], r1 = rowptr[node + 1];

  const uint2* __restrict__ yv = reinterpret_cast<const uint2*>(y);

  float a0 = 0.f, a1 = 0.f, a2 = 0.f, a3 = 0.f;
  float b0 = 0.f, b1 = 0.f, b2 = 0.f, b3 = 0.f;
  float c0 = 0.f, c1 = 0.f, c2 = 0.f, c3 = 0.f;
  float d0 = 0.f, d1 = 0.f, d2 = 0.f, d3 = 0.f;
  int k = r0;
  for (; k + 3 < r1; k += 4) {
    int ia = csr[k], ib = csr[k + 1], ic = csr[k + 2], id = csr[k + 3];
    uint2 ra = yv[ia * 4 + l];
    uint2 rb = yv[ib * 4 + l];
    uint2 rc = yv[ic * 4 + l];
    uint2 rd = yv[id * 4 + l];
    float2 fa0 = __half22float2(*reinterpret_cast<const __half2*>(&ra.x));
    float2 fa1 = __half22float2(*reinterpret_cast<const __half2*>(&ra.y));
    float2 fb0 = __half22float2(*reinterpret_cast<const __half2*>(&rb.x));
    float2 fb1 = __half22float2(*reinterpret_cast<const __half2*>(&rb.y));
    float2 fc0 = __half22float2(*reinterpret_cast<const __half2*>(&rc.x));
    float2 fc1 = __half22float2(*reinterpret_cast<const __half2*>(&rc.y));
    float2 fd0 = __half22float2(*reinterpret_cast<const __half2*>(&rd.x));
    float2 fd1 = __half22float2(*reinterpret_cast<const __half2*>(&rd.y));
    a0 += fa0.x; a1 += fa0.y; a2 += fa1.x; a3 += fa1.y;
    b0 += fb0.x; b1 += fb0.y; b2 += fb1.x; b3 += fb1.y;
    c0 += fc0.x; c1 += fc0.y; c2 += fc1.x; c3 += fc1.y;
    d0 += fd0.x; d1 += fd0.y; d2 += fd1.x; d3 += fd1.y;
  }
  for (; k < r1; ++k) {
    int ia = csr[k];
    uint2 ra = yv[ia * 4 + l];
    float2 fa0 = __half22float2(*reinterpret_cast<const __half2*>(&ra.x));
    float2 fa1 = __half22float2(*reinterpret_cast<const __half2*>(&ra.y));
    a0 += fa0.x; a1 += fa0.y; a2 += fa1.x; a3 += fa1.y;
  }
  float s0 = a0 + b0 + c0 + d0;
  float s1 = a1 + b1 + c1 + d1;
  float s2 = a2 + b2 + c2 + d2;
  float s3 = a3 + b3 + c3 + d3;
  float inv = 1.f / fmaxf((float)(r1 - r0), 1.f);

  int cbase = l * 4;
  float4 rr = *reinterpret_cast<const float4*>(&sb[cbase]);
  #pragma unroll
  for (int i = 0; i < DI; ++i) {
    float h = hin[node * DI + i];
    float4 w = *reinterpret_cast<const float4*>(&sWr[i * 16 + cbase]);
    rr.x += h * w.x; rr.y += h * w.y; rr.z += h * w.z; rr.w += h * w.w;
  }

  float ax = s0 * inv + rr.x;
  float ay = s1 * inv + rr.y;
  float az = s2 * inv + rr.z;
  float aw = s3 * inv + rr.w;
  float4 o;
  o.x = ax > 0.f ? ax : (__expf(ax) - 1.f);
  o.y = ay > 0.f ? ay : (__expf(ay) - 1.f);
  o.z = az > 0.f ? az : (__expf(az) - 1.f);
  o.w = aw > 0.f ? aw : (__expf(aw) - 1.f);
  *reinterpret_cast<float4*>(&outp[node * 16 + cbase]) = o;
}

// ---------------- fused 4-layer MLP ----------------
// Persistent blocks, 16 groups x 16 lanes, 4 nodes/group (the measured grid
// sweet spot). W1/W2 staged ONCE per block into LDS -> inner-loop weight reads
// are ds_read_b128 with 4-group wave broadcast (conflict-free), removing the
// ~200cy L1 latency from the critical path. W0/W3/biases stay global (L1-hot).

#define HSTRIDE 68

__device__ __forceinline__ float4 elu4(float4 a) {
  float4 r;
  r.x = a.x > 0.f ? a.x : (__expf(a.x) - 1.f);
  r.y = a.y > 0.f ? a.y : (__expf(a.y) - 1.f);
  r.z = a.z > 0.f ? a.z : (__expf(a.z) - 1.f);
  r.w = a.w > 0.f ? a.w : (__expf(a.w) - 1.f);
  return r;
}

__device__ __forceinline__ void fma16(float4& a, const float4 h,
                                      const float4 w0, const float4 w1,
                                      const float4 w2, const float4 w3) {
  a.x += h.x * w0.x + h.y * w1.x + h.z * w2.x + h.w * w3.x;
  a.y += h.x * w0.y + h.y * w1.y + h.z * w2.y + h.w * w3.y;
  a.z += h.x * w0.z + h.y * w1.z + h.z * w2.z + h.w * w3.z;
  a.w += h.x * w0.w + h.y * w1.w + h.z * w2.w + h.w * w3.w;
}

__global__ void __launch_bounds__(256) k_mlp(
    const float* __restrict__ xin,
    const float* __restrict__ W0, const float* __restrict__ B0,
    const float* __restrict__ W1, const float* __restrict__ B1,
    const float* __restrict__ W2, const float* __restrict__ B2,
    const float* __restrict__ W3, const float* __restrict__ B3,
    float* __restrict__ out, int n, int nchunks) {
  __shared__ __align__(16) float hrow[64 * HSTRIDE];  // 16 groups * 4 rows
  __shared__ __align__(16) float sW1[64 * 64];
  __shared__ __align__(16) float sW2[64 * 64];
  __shared__ __align__(16) float sW3T[4 * 64];        // W3 transposed: [c][i]
  int t = threadIdx.x;
  int l = t & 15;
  int gb = t >> 4;
  int row0 = gb * 4;

  for (int i = t; i < 64 * 64; i += 256) { sW1[i] = W1[i]; sW2[i] = W2[i]; }
  sW3T[(t & 3) * 64 + (t >> 2)] = W3[t];
  __syncthreads();

  for (int chunk = blockIdx.x; chunk < nchunks; chunk += gridDim.x) {
    int nodeBase = chunk * 64 + gb * 4;
    if (nodeBase >= n) continue;

    // stage 4 nodes * 16 floats = 16 float4; lane l covers float4 #l (intra-wave)
    {
      int nd = l >> 2;
      float4 v = make_float4(0.f, 0.f, 0.f, 0.f);
      if (nodeBase + nd < n)
        v = *reinterpret_cast<const float4*>(&xin[nodeBase * 16 + l * 4]);
      *reinterpret_cast<float4*>(&hrow[(row0 + nd) * HSTRIDE + (l & 3) * 4]) = v;
    }

    float4 acc0, acc1, acc2, acc3;

    // ---- layer0: 16 -> 64 (weights from global; 4KB, L1-hot) ----
    acc0 = *reinterpret_cast<const float4*>(&B0[4 * l]);
    acc1 = acc0; acc2 = acc0; acc3 = acc0;
    #pragma unroll
    for (int j = 0; j < 4; ++j) {
      float4 h0 = *reinterpret_cast<const float4*>(&hrow[(row0 + 0) * HSTRIDE + j * 4]);
      float4 h1 = *reinterpret_cast<const float4*>(&hrow[(row0 + 1) * HSTRIDE + j * 4]);
      float4 h2 = *reinterpret_cast<const float4*>(&hrow[(row0 + 2) * HSTRIDE + j * 4]);
      float4 h3 = *reinterpret_cast<const float4*>(&hrow[(row0 + 3) * HSTRIDE + j * 4]);
      float4 w0 = *reinterpret_cast<const float4*>(&W0[(4 * j + 0) * 64 + 4 * l]);
      float4 w1 = *reinterpret_cast<const float4*>(&W0[(4 * j + 1) * 64 + 4 * l]);
      float4 w2 = *reinterpret_cast<const float4*>(&W0[(4 * j + 2) * 64 + 4 * l]);
      float4 w3 = *reinterpret_cast<const float4*>(&W0[(4 * j + 3) * 64 + 4 * l]);
      fma16(acc0, h0, w0, w1, w2, w3);
      fma16(acc1, h1, w0, w1, w2, w3);
      fma16(acc2, h2, w0, w1, w2, w3);
      fma16(acc3, h3, w0, w1, w2, w3);
    }
    *reinterpret_cast<float4*>(&hrow[(row0 + 0) * HSTRIDE + l * 4]) = elu4(acc0);
    *reinterpret_cast<float4*>(&hrow[(row0 + 1) * HSTRIDE + l * 4]) = elu4(acc1);
    *reinterpret_cast<float4*>(&hrow[(row0 + 2) * HSTRIDE + l * 4]) = elu4(acc2);
    *reinterpret_cast<float4*>(&hrow[(row0 + 3) * HSTRIDE + l * 4]) = elu4(acc3);

    // ---- layers 1 & 2: 64 -> 64 (weights from LDS) ----
    const float* Ws[2] = {sW1, sW2};
    const float* Bs[2] = {B1, B2};
    #pragma unroll
    for (int layer = 0; layer < 2; ++layer) {
      const float* __restrict__ W = Ws[layer];
      acc0 = *reinterpret_cast<const float4*>(&Bs[layer][4 * l]);
      acc1 = acc0; acc2 = acc0; acc3 = acc0;
      #pragma unroll 4
      for (int j = 0; j < 16; ++j) {
        float4 h0 = *reinterpret_cast<const float4*>(&hrow[(row0 + 0) * HSTRIDE + j * 4]);
        float4 h1 = *reinterpret_cast<const float4*>(&hrow[(row0 + 1) * HSTRIDE + j * 4]);
        float4 h2 = *reinterpret_cast<const float4*>(&hrow[(row0 + 2) * HSTRIDE + j * 4]);
        float4 h3 = *reinterpret_cast<const float4*>(&hrow[(row0 + 3) * HSTRIDE + j * 4]);
        float4 w0 = *reinterpret_cast<const float4*>(&W[(4 * j + 0) * 64 + 4 * l]);
        float4 w1 = *reinterpret_cast<const float4*>(&W[(4 * j + 1) * 64 + 4 * l]);
        float4 w2 = *reinterpret_cast<const float4*>(&W[(4 * j + 2) * 64 + 4 * l]);
        float4 w3 = *reinterpret_cast<const float4*>(&W[(4 * j + 3) * 64 + 4 * l]);
        fma16(acc0, h0, w0, w1, w2, w3);
        fma16(acc1, h1, w0, w1, w2, w3);
        fma16(acc2, h2, w0, w1, w2, w3);
        fma16(acc3, h3, w0, w1, w2, w3);
      }
      *reinterpret_cast<float4*>(&hrow[(row0 + 0) * HSTRIDE + l * 4]) = elu4(acc0);
      *reinterpret_cast<float4*>(&hrow[(row0 + 1) * HSTRIDE + l * 4]) = elu4(acc1);
      *reinterpret_cast<float4*>(&hrow[(row0 + 2) * HSTRIDE + l * 4]) = elu4(acc2);
      *reinterpret_cast<float4*>(&hrow[(row0 + 3) * HSTRIDE + l * 4]) = elu4(acc3);
    }

    // ---- layer3: 64 -> 4; lane l handles node (l>>2), channel (l&3) ----
    {
      int nd = l >> 2, c = l & 3;
      float acc = B3[c];
      #pragma unroll 4
      for (int i = 0; i < 16; ++i) {
        float4 h = *reinterpret_cast<const float4*>(&hrow[(row0 + nd) * HSTRIDE + i * 4]);
        float4 w = *reinterpret_cast<const float4*>(&sW3T[c * 64 + i * 4]);
        acc += h.x * w.x + h.y * w.y + h.z * w.z + h.w * w.w;
      }
      if (nodeBase + nd < n) out[(nodeBase + nd) * 4 + c] = acc;
    }
  }
}

// ---------------- launch ----------------

extern "C" void kernel_launch(void* const* d_in, const int* in_sizes, int n_in,
                              void* d_out, int out_size, void* d_ws, size_t ws_size,
                              hipStream_t stream) {
  const float* x   = (const float*)d_in[0];
  const int*   ei  = (const int*)d_in[1];
  const float* Wl0 = (const float*)d_in[2];
  const float* Wr0 = (const float*)d_in[3];
  const float* bl0 = (const float*)d_in[4];
  const float* Wl1 = (const float*)d_in[5];
  const float* Wr1 = (const float*)d_in[6];
  const float* bl1 = (const float*)d_in[7];
  const float* Wl2 = (const float*)d_in[8];
  const float* Wr2 = (const float*)d_in[9];
  const float* bl2 = (const float*)d_in[10];
  const float* LW0 = (const float*)d_in[11];
  const float* LB0 = (const float*)d_in[12];
  const float* LW1 = (const float*)d_in[13];
  const float* LB1 = (const float*)d_in[14];
  const float* LW2 = (const float*)d_in[15];
  const float* LB2 = (const float*)d_in[16];
  const float* LW3 = (const float*)d_in[17];
  const float* LB3 = (const float*)d_in[18];
  float* out = (float*)d_out;

  const int N_ = in_sizes[0] / 32;   // 100000
  const int E_ = in_sizes[1] / 2;    // 3200000

  const int NB = (N_ + (1 << BSH) - 1) >> BSH;        // 391 buckets
  const int chunk = (E_ + GPART - 1) / GPART;
  const int n2 = NB * GPART;                           // 200192
  const int nb2 = (n2 + 255) / 256;                    // 782 <= 1024

  char* wsp = (char*)d_ws;
  int* cnt    = (int*)wsp;  wsp += sizeof(int) * (size_t)n2;
  int* off    = (int*)wsp;  wsp += sizeof(int) * (size_t)n2;
  int* part   = (int*)wsp;  wsp += sizeof(int) * 1024;
  int* temp   = (int*)wsp;  wsp += sizeof(int) * (size_t)E_;   // 12.8 MB, dead after k_fine
  int* csr    = (int*)wsp;  wsp += sizeof(int) * (size_t)E_;
  size_t hBytes = sizeof(float) * (size_t)N_ * DCONV;          // 6.4 MB
  float* Ha   = (float*)wsp; wsp += hBytes;
  int* rowptr = (int*)wsp;  wsp += sizeof(int) * (size_t)(N_ + 1);
  // reuse temp: y16 (3.2 MB) + Hb (6.4 MB) <= 12.8 MB
  __half* y16 = (__half*)temp;
  float*  Hb  = (float*)((char*)temp + sizeof(__half) * (size_t)N_ * DCONV);

  // CSR build
  k_hist<<<GPART, 256, 0, stream>>>(ei, E_, NB, chunk, cnt);
  k_block_sums<<<nb2, 256, 0, stream>>>(cnt, n2, part);
  k_scan_part<<<1, 1024, 0, stream>>>(part, nb2);
  k_excl_apply<<<nb2, 256, 0, stream>>>(cnt, n2, part, off);
  k_scatter<<<GPART, 256, 0, stream>>>(ei, E_, NB, chunk, off, temp);
  k_fine<<<NB, 256, 0, stream>>>(temp, off, NB, E_, N_, rowptr, csr);

  int nbX = (N_ * 16 + 255) / 256;   // xform grids
  int nbA = (N_ * 4 + 255) / 256;    // agg grids

  // conv0: x -> Ha
  k_xform32h<<<nbX, 256, 0, stream>>>(x, Wl0, y16, N_);
  k_agg<32><<<nbA, 256, 0, stream>>>(y16, x, Wr0, bl0, rowptr, csr, Ha, N_);
  // conv1: Ha -> Hb
  k_xform16h<<<nbX, 256, 0, stream>>>(Ha, Wl1, y16, N_);
  k_agg<16><<<nbA, 256, 0, stream>>>(y16, Ha, Wr1, bl1, rowptr, csr, Hb, N_);
  // conv2: Hb -> Ha
  k_xform16h<<<nbX, 256, 0, stream>>>(Hb, Wl2, y16, N_);
  k_agg<16><<<nbA, 256, 0, stream>>>(y16, Hb, Wr2, bl2, rowptr, csr, Ha, N_);

  // MLP: persistent blocks, 64 nodes per chunk
  int nchunks = (N_ + 63) / 64;          // 1563
  int nbM = 768;                          // 3 blocks/CU target
  if (nbM > nchunks) nbM = nchunks;
  k_mlp<<<nbM, 256, 0, stream>>>(Ha, LW0, LB0, LW1, LB1, LW2, LB2, LW3, LB3, out, N_, nchunks);
}

// Round 10
// 222.893 us; speedup vs baseline: 1.1754x; 1.1372x over previous
//
#include <hip/hip_runtime.h>
#include <hip/hip_fp16.h>
#include <math.h>

#define DCONV 16
#define BSH 8            // nodes per bucket = 256
#define GPART 512        // partition blocks (parallelism for hist/scatter)
#define MAXNB 512

// ---------------- bucketed CSR build ----------------

__global__ void k_hist(const int* __restrict__ ei, int E, int nb_buckets, int chunk,
                       int* __restrict__ cnt) {
  __shared__ int hist[MAXNB];
  int g = blockIdx.x;
  for (int i = threadIdx.x; i < nb_buckets; i += 256) hist[i] = 0;
  __syncthreads();
  int e0 = g * chunk, e1 = min(e0 + chunk, E);
  for (int e = e0 + threadIdx.x; e < e1; e += 256)
    atomicAdd(&hist[ei[E + e] >> BSH], 1);
  __syncthreads();
  for (int i = threadIdx.x; i < nb_buckets; i += 256)
    cnt[i * GPART + g] = hist[i];
}

__global__ void k_block_sums(const int* __restrict__ in, int n, int* __restrict__ part) {
  int i = blockIdx.x * 256 + threadIdx.x;
  int v = (i < n) ? in[i] : 0;
  #pragma unroll
  for (int off = 32; off > 0; off >>= 1) v += __shfl_down(v, off, 64);
  __shared__ int ws[4];
  if ((threadIdx.x & 63) == 0) ws[threadIdx.x >> 6] = v;
  __syncthreads();
  if (threadIdx.x == 0) part[blockIdx.x] = ws[0] + ws[1] + ws[2] + ws[3];
}

// single block, 1024 threads; nb <= 1024
__global__ void k_scan_part(int* __restrict__ part, int nb) {
  __shared__ int s[1024];
  int t = threadIdx.x;
  int v = (t < nb) ? part[t] : 0;
  s[t] = v;
  __syncthreads();
  for (int off = 1; off < 1024; off <<= 1) {
    int u = (t >= off) ? s[t - off] : 0;
    __syncthreads();
    s[t] += u;
    __syncthreads();
  }
  if (t < nb) part[t] = s[t] - v;  // exclusive prefix
}

__global__ void k_excl_apply(const int* __restrict__ in, int n, const int* __restrict__ part,
                             int* __restrict__ out) {
  __shared__ int s[256];
  int t = threadIdx.x;
  int i = blockIdx.x * 256 + t;
  int v = (i < n) ? in[i] : 0;
  s[t] = v;
  __syncthreads();
  for (int off = 1; off < 256; off <<= 1) {
    int u = (t >= off) ? s[t - off] : 0;
    __syncthreads();
    s[t] += u;
    __syncthreads();
  }
  if (i < n) out[i] = s[t] - v + part[blockIdx.x];
}

__global__ void k_scatter(const int* __restrict__ ei, int E, int nb_buckets, int chunk,
                          const int* __restrict__ off, int* __restrict__ temp) {
  __shared__ int cur[MAXNB];
  int g = blockIdx.x;
  for (int i = threadIdx.x; i < nb_buckets; i += 256) cur[i] = off[i * GPART + g];
  __syncthreads();
  int e0 = g * chunk, e1 = min(e0 + chunk, E);
  for (int e = e0 + threadIdx.x; e < e1; e += 256) {
    int s = ei[e];
    int d = ei[E + e];
    int b = d >> BSH;
    int pos = atomicAdd(&cur[b], 1);
    temp[pos] = (s << BSH) | (d & ((1 << BSH) - 1));
  }
}

__global__ void k_fine(const int* __restrict__ temp, const int* __restrict__ off,
                       int nb_buckets, int E, int n,
                       int* __restrict__ rowptr, int* __restrict__ csr) {
  __shared__ int hist[1 << BSH];
  __shared__ int cur[1 << BSH];
  int b = blockIdx.x, t = threadIdx.x;
  int lo = off[b * GPART];
  int hi = (b == nb_buckets - 1) ? E : off[(b + 1) * GPART];
  hist[t] = 0;
  __syncthreads();
  for (int e = lo + t; e < hi; e += 256)
    atomicAdd(&hist[temp[e] & 255], 1);
  __syncthreads();
  int v = hist[t];
  cur[t] = v;
  __syncthreads();
  for (int offm = 1; offm < 256; offm <<= 1) {
    int u = (t >= offm) ? cur[t - offm] : 0;
    __syncthreads();
    cur[t] += u;
    __syncthreads();
  }
  int excl = cur[t] - v;
  int node = (b << BSH) + t;
  if (node < n) rowptr[node] = lo + excl;
  if (b == nb_buckets - 1 && t == 0) rowptr[n] = hi;
  cur[t] = lo + excl;
  __syncthreads();
  for (int e = lo + t; e < hi; e += 256) {
    int p = temp[e];
    int pos = atomicAdd(&cur[p & 255], 1);
    csr[pos] = p >> BSH;
  }
}

// ---------------- pre-transform: y = fp16(h @ Wl) ----------------

__global__ void k_xform32h(const float* __restrict__ xin,
                           const float* __restrict__ Wl,
                           __half* __restrict__ y, int n) {
  __shared__ float sWl[32 * 16];
  int t = threadIdx.x;
  for (int i = t; i < 32 * 16; i += 256) sWl[i] = Wl[i];
  __syncthreads();
  int l = t & 15;
  int base = (t & 63) & ~15;
  int node = (blockIdx.x * 256 + t) >> 4;
  if (node >= n) return;
  float x0 = xin[node * 32 + l];
  float x1 = xin[node * 32 + 16 + l];
  float ay = 0.f;
  #pragma unroll
  for (int i = 0; i < 16; ++i) {
    float v0 = __shfl(x0, base + i, 64);
    float v1 = __shfl(x1, base + i, 64);
    ay += v0 * sWl[i * 16 + l] + v1 * sWl[(16 + i) * 16 + l];
  }
  y[node * 16 + l] = __float2half_rn(ay);
}

__global__ void k_xform16h(const float* __restrict__ hin,
                           const float* __restrict__ Wl,
                           __half* __restrict__ y, int n) {
  __shared__ float sWl[16 * 16];
  int t = threadIdx.x;
  for (int i = t; i < 16 * 16; i += 256) sWl[i] = Wl[i];
  __syncthreads();
  int l = t & 15;
  int base = (t & 63) & ~15;
  int node = (blockIdx.x * 256 + t) >> 4;
  if (node >= n) return;
  float x0 = hin[node * 16 + l];
  float ay = 0.f;
  #pragma unroll
  for (int i = 0; i < 16; ++i) {
    float v0 = __shfl(x0, base + i, 64);
    ay += v0 * sWl[i * 16 + l];
  }
  y[node * 16 + l] = __float2half_rn(ay);
}

// ---------------- aggregate: out = elu(mean_gather(y16) + h@Wr + b) ----------------

template <int DI>
__global__ void k_agg(const __half* __restrict__ y, const float* __restrict__ hin,
                      const float* __restrict__ Wr, const float* __restrict__ bias,
                      const int* __restrict__ rowptr, const int* __restrict__ csr,
                      float* __restrict__ outp, int n) {
  __shared__ __align__(16) float sWr[DI * 16];
  __shared__ float sb[16];
  {
    int tt = threadIdx.x;
    for (int i = tt; i < DI * 16; i += 256) sWr[i] = Wr[i];
    if (tt < 16) sb[tt] = bias[tt];
  }
  __syncthreads();

  int t = blockIdx.x * 256 + threadIdx.x;
  int l = t & 3;
  int node = t >> 2;
  if (node >= n) return;
  int r0 = rowptr[node], r1 = rowptr[node + 1];

  const uint2* __restrict__ yv = reinterpret_cast<const uint2*>(y);

  float a0 = 0.f, a1 = 0.f, a2 = 0.f, a3 = 0.f;
  float b0 = 0.f, b1 = 0.f, b2 = 0.f, b3 = 0.f;
  float c0 = 0.f, c1 = 0.f, c2 = 0.f, c3 = 0.f;
  float d0 = 0.f, d1 = 0.f, d2 = 0.f, d3 = 0.f;
  int k = r0;
  for (; k + 3 < r1; k += 4) {
    int ia = csr[k], ib = csr[k + 1], ic = csr[k + 2], id = csr[k + 3];
    uint2 ra = yv[ia * 4 + l];
    uint2 rb = yv[ib * 4 + l];
    uint2 rc = yv[ic * 4 + l];
    uint2 rd = yv[id * 4 + l];
    float2 fa0 = __half22float2(*reinterpret_cast<const __half2*>(&ra.x));
    float2 fa1 = __half22float2(*reinterpret_cast<const __half2*>(&ra.y));
    float2 fb0 = __half22float2(*reinterpret_cast<const __half2*>(&rb.x));
    float2 fb1 = __half22float2(*reinterpret_cast<const __half2*>(&rb.y));
    float2 fc0 = __half22float2(*reinterpret_cast<const __half2*>(&rc.x));
    float2 fc1 = __half22float2(*reinterpret_cast<const __half2*>(&rc.y));
    float2 fd0 = __half22float2(*reinterpret_cast<const __half2*>(&rd.x));
    float2 fd1 = __half22float2(*reinterpret_cast<const __half2*>(&rd.y));
    a0 += fa0.x; a1 += fa0.y; a2 += fa1.x; a3 += fa1.y;
    b0 += fb0.x; b1 += fb0.y; b2 += fb1.x; b3 += fb1.y;
    c0 += fc0.x; c1 += fc0.y; c2 += fc1.x; c3 += fc1.y;
    d0 += fd0.x; d1 += fd0.y; d2 += fd1.x; d3 += fd1.y;
  }
  for (; k < r1; ++k) {
    int ia = csr[k];
    uint2 ra = yv[ia * 4 + l];
    float2 fa0 = __half22float2(*reinterpret_cast<const __half2*>(&ra.x));
    float2 fa1 = __half22float2(*reinterpret_cast<const __half2*>(&ra.y));
    a0 += fa0.x; a1 += fa0.y; a2 += fa1.x; a3 += fa1.y;
  }
  float s0 = a0 + b0 + c0 + d0;
  float s1 = a1 + b1 + c1 + d1;
  float s2 = a2 + b2 + c2 + d2;
  float s3 = a3 + b3 + c3 + d3;
  float inv = 1.f / fmaxf((float)(r1 - r0), 1.f);

  int cbase = l * 4;
  float4 rr = *reinterpret_cast<const float4*>(&sb[cbase]);
  #pragma unroll
  for (int i = 0; i < DI; ++i) {
    float h = hin[node * DI + i];
    float4 w = *reinterpret_cast<const float4*>(&sWr[i * 16 + cbase]);
    rr.x += h * w.x; rr.y += h * w.y; rr.z += h * w.z; rr.w += h * w.w;
  }

  float ax = s0 * inv + rr.x;
  float ay = s1 * inv + rr.y;
  float az = s2 * inv + rr.z;
  float aw = s3 * inv + rr.w;
  float4 o;
  o.x = ax > 0.f ? ax : (__expf(ax) - 1.f);
  o.y = ay > 0.f ? ay : (__expf(ay) - 1.f);
  o.z = az > 0.f ? az : (__expf(az) - 1.f);
  o.w = aw > 0.f ? aw : (__expf(aw) - 1.f);
  *reinterpret_cast<float4*>(&outp[node * 16 + cbase]) = o;
}

// ---------------- fused 4-layer MLP via MFMA ----------------
// One wave owns 16 nodes. All weight B-fragments persist in VGPRs (~80),
// loaded once per block and amortized over a grid-stride loop. Inter-layer
// transposes go through a per-wave col-major f16 LDS scratch (stride 20
// halves -> conflict-free writes and reads; hand-checked). No barriers in
// the loop (wave-private buffers; RAW ordering via data dependence).
// mfma_f32_16x16x16_f16 layouts (classic CDNA):
//   A: lane l holds A[row=l&15][k=(l>>4)*4+j]
//   B: lane l holds B[k=(l>>4)*4+j][col=l&15]
//   D: lane l holds D[row=(l>>4)*4+i][col=l&15]   (m89-verified)

typedef _Float16 f16x4 __attribute__((ext_vector_type(4)));
typedef float f32x4 __attribute__((ext_vector_type(4)));

#define MFMA16(a, b, c) __builtin_amdgcn_mfma_f32_16x16x16f16(a, b, c, 0, 0, 0)
#define CSTRIDE 20  // halves per LDS column slot

__global__ void __launch_bounds__(256) k_mlp(
    const float* __restrict__ xin,
    const float* __restrict__ W0, const float* __restrict__ B0,
    const float* __restrict__ W1, const float* __restrict__ B1,
    const float* __restrict__ W2, const float* __restrict__ B2,
    const float* __restrict__ W3, const float* __restrict__ B3,
    float* __restrict__ out, int n, int nchunks) {
  __shared__ __align__(16) _Float16 hbuf[4][2][64 * CSTRIDE];  // 20.5 KB
  int t = threadIdx.x;
  int w = t >> 6;        // wave in block
  int lane = t & 63;
  int row = lane & 15;   // A-row / D-col index
  int kg = lane >> 4;    // k-group

  // ---- persistent B fragments + biases ----
  f16x4 b0f[4], b1f[4][4], b2f[4][4], b3f[4];
  float bs0[4], bs1v[4], bs2v[4];
  #pragma unroll
  for (int nt = 0; nt < 4; ++nt) {
    #pragma unroll
    for (int j = 0; j < 4; ++j)
      b0f[nt][j] = (_Float16)W0[(kg * 4 + j) * 64 + nt * 16 + row];
    bs0[nt] = B0[nt * 16 + row];
    bs1v[nt] = B1[nt * 16 + row];
    bs2v[nt] = B2[nt * 16 + row];
  }
  #pragma unroll
  for (int ks = 0; ks < 4; ++ks)
    #pragma unroll
    for (int nt = 0; nt < 4; ++nt)
      #pragma unroll
      for (int j = 0; j < 4; ++j) {
        b1f[ks][nt][j] = (_Float16)W1[(ks * 16 + kg * 4 + j) * 64 + nt * 16 + row];
        b2f[ks][nt][j] = (_Float16)W2[(ks * 16 + kg * 4 + j) * 64 + nt * 16 + row];
      }
  #pragma unroll
  for (int ks = 0; ks < 4; ++ks)
    #pragma unroll
    for (int j = 0; j < 4; ++j)
      b3f[ks][j] = (row < 4) ? (_Float16)W3[(ks * 16 + kg * 4 + j) * 4 + row]
                             : (_Float16)0.f;
  float bs3 = (row < 4) ? B3[row] : 0.f;

  _Float16* hb0 = &hbuf[w][0][0];
  _Float16* hb1 = &hbuf[w][1][0];

  for (int c = blockIdx.x; c < nchunks; c += gridDim.x) {
    int nodeBase = c * 64 + w * 16;
    if (nodeBase >= n) continue;

    // ---- layer0: 16 -> 64 ; A direct from global ----
    int nd = nodeBase + row;
    if (nd >= n) nd = n - 1;
    float4 xv = *reinterpret_cast<const float4*>(&xin[nd * 16 + kg * 4]);
    f16x4 a0;
    a0[0] = (_Float16)xv.x; a0[1] = (_Float16)xv.y;
    a0[2] = (_Float16)xv.z; a0[3] = (_Float16)xv.w;
    #pragma unroll
    for (int nt = 0; nt < 4; ++nt) {
      f32x4 acc = {bs0[nt], bs0[nt], bs0[nt], bs0[nt]};
      acc = MFMA16(a0, b0f[nt], acc);
      f16x4 hv;
      #pragma unroll
      for (int i = 0; i < 4; ++i) {
        float v = acc[i];
        v = v > 0.f ? v : (__expf(v) - 1.f);
        hv[i] = (_Float16)v;
      }
      *reinterpret_cast<f16x4*>(&hb0[(nt * 16 + row) * CSTRIDE + kg * 4]) = hv;
    }

    // ---- layer1: hb0 -> hb1 ----
    {
      f16x4 a[4];
      #pragma unroll
      for (int ks = 0; ks < 4; ++ks)
        #pragma unroll
        for (int j = 0; j < 4; ++j)
          a[ks][j] = hb0[(ks * 16 + kg * 4 + j) * CSTRIDE + row];
      #pragma unroll
      for (int nt = 0; nt < 4; ++nt) {
        f32x4 acc = {bs1v[nt], bs1v[nt], bs1v[nt], bs1v[nt]};
        #pragma unroll
        for (int ks = 0; ks < 4; ++ks) acc = MFMA16(a[ks], b1f[ks][nt], acc);
        f16x4 hv;
        #pragma unroll
        for (int i = 0; i < 4; ++i) {
          float v = acc[i];
          v = v > 0.f ? v : (__expf(v) - 1.f);
          hv[i] = (_Float16)v;
        }
        *reinterpret_cast<f16x4*>(&hb1[(nt * 16 + row) * CSTRIDE + kg * 4]) = hv;
      }
    }

    // ---- layer2: hb1 -> hb0 ----
    {
      f16x4 a[4];
      #pragma unroll
      for (int ks = 0; ks < 4; ++ks)
        #pragma unroll
        for (int j = 0; j < 4; ++j)
          a[ks][j] = hb1[(ks * 16 + kg * 4 + j) * CSTRIDE + row];
      #pragma unroll
      for (int nt = 0; nt < 4; ++nt) {
        f32x4 acc = {bs2v[nt], bs2v[nt], bs2v[nt], bs2v[nt]};
        #pragma unroll
        for (int ks = 0; ks < 4; ++ks) acc = MFMA16(a[ks], b2f[ks][nt], acc);
        f16x4 hv;
        #pragma unroll
        for (int i = 0; i < 4; ++i) {
          float v = acc[i];
          v = v > 0.f ? v : (__expf(v) - 1.f);
          hv[i] = (_Float16)v;
        }
        *reinterpret_cast<f16x4*>(&hb0[(nt * 16 + row) * CSTRIDE + kg * 4]) = hv;
      }
    }

    // ---- layer3: 64 -> 4 (cols 0..3 valid) ----
    {
      f16x4 a[4];
      #pragma unroll
      for (int ks = 0; ks < 4; ++ks)
        #pragma unroll
        for (int j = 0; j < 4; ++j)
          a[ks][j] = hb0[(ks * 16 + kg * 4 + j) * CSTRIDE + row];
      f32x4 acc = {bs3, bs3, bs3, bs3};
      #pragma unroll
      for (int ks = 0; ks < 4; ++ks) acc = MFMA16(a[ks], b3f[ks], acc);
      if (row < 4) {
        #pragma unroll
        for (int i = 0; i < 4; ++i) {
          int nd2 = nodeBase + kg * 4 + i;
          if (nd2 < n) out[nd2 * 4 + row] = acc[i];
        }
      }
    }
  }
}

// ---------------- launch ----------------

extern "C" void kernel_launch(void* const* d_in, const int* in_sizes, int n_in,
                              void* d_out, int out_size, void* d_ws, size_t ws_size,
                              hipStream_t stream) {
  const float* x   = (const float*)d_in[0];
  const int*   ei  = (const int*)d_in[1];
  const float* Wl0 = (const float*)d_in[2];
  const float* Wr0 = (const float*)d_in[3];
  const float* bl0 = (const float*)d_in[4];
  const float* Wl1 = (const float*)d_in[5];
  const float* Wr1 = (const float*)d_in[6];
  const float* bl1 = (const float*)d_in[7];
  const float* Wl2 = (const float*)d_in[8];
  const float* Wr2 = (const float*)d_in[9];
  const float* bl2 = (const float*)d_in[10];
  const float* LW0 = (const float*)d_in[11];
  const float* LB0 = (const float*)d_in[12];
  const float* LW1 = (const float*)d_in[13];
  const float* LB1 = (const float*)d_in[14];
  const float* LW2 = (const float*)d_in[15];
  const float* LB2 = (const float*)d_in[16];
  const float* LW3 = (const float*)d_in[17];
  const float* LB3 = (const float*)d_in[18];
  float* out = (float*)d_out;

  const int N_ = in_sizes[0] / 32;   // 100000
  const int E_ = in_sizes[1] / 2;    // 3200000

  const int NB = (N_ + (1 << BSH) - 1) >> BSH;        // 391 buckets
  const int chunk = (E_ + GPART - 1) / GPART;
  const int n2 = NB * GPART;                           // 200192
  const int nb2 = (n2 + 255) / 256;                    // 782 <= 1024

  char* wsp = (char*)d_ws;
  int* cnt    = (int*)wsp;  wsp += sizeof(int) * (size_t)n2;
  int* off    = (int*)wsp;  wsp += sizeof(int) * (size_t)n2;
  int* part   = (int*)wsp;  wsp += sizeof(int) * 1024;
  int* temp   = (int*)wsp;  wsp += sizeof(int) * (size_t)E_;   // 12.8 MB, dead after k_fine
  int* csr    = (int*)wsp;  wsp += sizeof(int) * (size_t)E_;
  size_t hBytes = sizeof(float) * (size_t)N_ * DCONV;          // 6.4 MB
  float* Ha   = (float*)wsp; wsp += hBytes;
  int* rowptr = (int*)wsp;  wsp += sizeof(int) * (size_t)(N_ + 1);
  // reuse temp: y16 (3.2 MB) + Hb (6.4 MB) <= 12.8 MB
  __half* y16 = (__half*)temp;
  float*  Hb  = (float*)((char*)temp + sizeof(__half) * (size_t)N_ * DCONV);

  // CSR build
  k_hist<<<GPART, 256, 0, stream>>>(ei, E_, NB, chunk, cnt);
  k_block_sums<<<nb2, 256, 0, stream>>>(cnt, n2, part);
  k_scan_part<<<1, 1024, 0, stream>>>(part, nb2);
  k_excl_apply<<<nb2, 256, 0, stream>>>(cnt, n2, part, off);
  k_scatter<<<GPART, 256, 0, stream>>>(ei, E_, NB, chunk, off, temp);
  k_fine<<<NB, 256, 0, stream>>>(temp, off, NB, E_, N_, rowptr, csr);

  int nbX = (N_ * 16 + 255) / 256;   // xform grids
  int nbA = (N_ * 4 + 255) / 256;    // agg grids

  // conv0: x -> Ha
  k_xform32h<<<nbX, 256, 0, stream>>>(x, Wl0, y16, N_);
  k_agg<32><<<nbA, 256, 0, stream>>>(y16, x, Wr0, bl0, rowptr, csr, Ha, N_);
  // conv1: Ha -> Hb
  k_xform16h<<<nbX, 256, 0, stream>>>(Ha, Wl1, y16, N_);
  k_agg<16><<<nbA, 256, 0, stream>>>(y16, Ha, Wr1, bl1, rowptr, csr, Hb, N_);
  // conv2: Hb -> Ha
  k_xform16h<<<nbX, 256, 0, stream>>>(Hb, Wl2, y16, N_);
  k_agg<16><<<nbA, 256, 0, stream>>>(y16, Hb, Wr2, bl2, rowptr, csr, Ha, N_);

  // MLP: MFMA, one wave per 16 nodes, grid-stride
  int nchunks = (N_ + 63) / 64;      // 1563
  int nbM = 512;                      // 2 blocks/CU, B-frags amortized ~3x
  if (nbM > nchunks) nbM = nchunks;
  k_mlp<<<nbM, 256, 0, stream>>>(Ha, LW0, LB0, LW1, LB1, LW2, LB2, LW3, LB3, out, N_, nchunks);
}

// Round 11
// 216.068 us; speedup vs baseline: 1.2125x; 1.0316x over previous
//
#include <hip/hip_runtime.h>
#include <hip/hip_fp16.h>
#include <math.h>

#define DCONV 16
#define BSH 8            // nodes per bucket = 256
#define GPART 512        // partition blocks (parallelism for hist/scatter)
#define GSH 9            // log2(GPART)
#define MAXNB 512

// ---------------- bucketed CSR build ----------------

__global__ void __launch_bounds__(512) k_hist(const int* __restrict__ ei, int E,
                                              int nb_buckets, int chunk,
                                              int* __restrict__ cnt) {
  __shared__ int hist[MAXNB];
  int g = blockIdx.x;
  for (int i = threadIdx.x; i < nb_buckets; i += 512) hist[i] = 0;
  __syncthreads();
  int e0 = g * chunk, e1 = min(e0 + chunk, E);
  for (int e = e0 + threadIdx.x; e < e1; e += 512)
    atomicAdd(&hist[ei[E + e] >> BSH], 1);
  __syncthreads();
  for (int i = threadIdx.x; i < nb_buckets; i += 512)
    cnt[i * GPART + g] = hist[i];
}

__global__ void k_block_sums(const int* __restrict__ in, int n, int* __restrict__ part) {
  int i = blockIdx.x * 256 + threadIdx.x;
  int v = (i < n) ? in[i] : 0;
  #pragma unroll
  for (int off = 32; off > 0; off >>= 1) v += __shfl_down(v, off, 64);
  __shared__ int ws[4];
  if ((threadIdx.x & 63) == 0) ws[threadIdx.x >> 6] = v;
  __syncthreads();
  if (threadIdx.x == 0) part[blockIdx.x] = ws[0] + ws[1] + ws[2] + ws[3];
}

// single block, 1024 threads; nb <= 1024
__global__ void k_scan_part(int* __restrict__ part, int nb) {
  __shared__ int s[1024];
  int t = threadIdx.x;
  int v = (t < nb) ? part[t] : 0;
  s[t] = v;
  __syncthreads();
  for (int off = 1; off < 1024; off <<= 1) {
    int u = (t >= off) ? s[t - off] : 0;
    __syncthreads();
    s[t] += u;
    __syncthreads();
  }
  if (t < nb) part[t] = s[t] - v;  // exclusive prefix
}

// writes TRANSPOSED offsets: offT[g * nb_buckets + b]
__global__ void k_excl_apply(const int* __restrict__ in, int n, const int* __restrict__ part,
                             int* __restrict__ outT, int nb_buckets) {
  __shared__ int s[256];
  int t = threadIdx.x;
  int i = blockIdx.x * 256 + t;
  int v = (i < n) ? in[i] : 0;
  s[t] = v;
  __syncthreads();
  for (int off = 1; off < 256; off <<= 1) {
    int u = (t >= off) ? s[t - off] : 0;
    __syncthreads();
    s[t] += u;
    __syncthreads();
  }
  if (i < n) {
    int excl = s[t] - v + part[blockIdx.x];
    int b = i >> GSH;
    int g = i & (GPART - 1);
    outT[g * nb_buckets + b] = excl;
  }
}

__global__ void __launch_bounds__(512) k_scatter(const int* __restrict__ ei, int E,
                                                 int nb_buckets, int chunk,
                                                 const int* __restrict__ offT,
                                                 int* __restrict__ temp) {
  __shared__ int cur[MAXNB];
  int g = blockIdx.x;
  for (int i = threadIdx.x; i < nb_buckets; i += 512) cur[i] = offT[g * nb_buckets + i];
  __syncthreads();
  int e0 = g * chunk, e1 = min(e0 + chunk, E);
  for (int e = e0 + threadIdx.x; e < e1; e += 512) {
    int s = ei[e];
    int d = ei[E + e];
    int b = d >> BSH;
    int pos = atomicAdd(&cur[b], 1);
    temp[pos] = (s << BSH) | (d & ((1 << BSH) - 1));
  }
}

__global__ void __launch_bounds__(512) k_fine(const int* __restrict__ temp,
                                              const int* __restrict__ offT,
                                              int nb_buckets, int E, int n,
                                              int* __restrict__ rowptr, int* __restrict__ csr) {
  __shared__ int hist[1 << BSH];
  __shared__ int cur[1 << BSH];
  int b = blockIdx.x, t = threadIdx.x;
  int lo = offT[b];                                      // g=0 row of offT
  int hi = (b == nb_buckets - 1) ? E : offT[b + 1];
  if (t < 256) hist[t] = 0;
  __syncthreads();
  for (int e = lo + t; e < hi; e += 512)
    atomicAdd(&hist[temp[e] & 255], 1);
  __syncthreads();
  int v = 0;
  if (t < 256) { v = hist[t]; cur[t] = v; }
  __syncthreads();
  for (int offm = 1; offm < 256; offm <<= 1) {
    int u = (t >= offm && t < 256) ? cur[t - offm] : 0;
    __syncthreads();
    if (t < 256) cur[t] += u;
    __syncthreads();
  }
  if (t < 256) {
    int excl = cur[t] - v;
    int node = (b << BSH) + t;
    if (node < n) rowptr[node] = lo + excl;
    cur[t] = lo + excl;
  }
  if (b == nb_buckets - 1 && t == 0) rowptr[n] = hi;
  __syncthreads();
  for (int e = lo + t; e < hi; e += 512) {
    int p = temp[e];
    int pos = atomicAdd(&cur[p & 255], 1);
    csr[pos] = p >> BSH;
  }
}

// ---------------- pre-transform: y = fp16(h @ Wl) ----------------

__global__ void k_xform32h(const float* __restrict__ xin,
                           const float* __restrict__ Wl,
                           __half* __restrict__ y, int n) {
  __shared__ float sWl[32 * 16];
  int t = threadIdx.x;
  for (int i = t; i < 32 * 16; i += 256) sWl[i] = Wl[i];
  __syncthreads();
  int l = t & 15;
  int base = (t & 63) & ~15;
  int node = (blockIdx.x * 256 + t) >> 4;
  if (node >= n) return;
  float x0 = xin[node * 32 + l];
  float x1 = xin[node * 32 + 16 + l];
  float ay = 0.f;
  #pragma unroll
  for (int i = 0; i < 16; ++i) {
    float v0 = __shfl(x0, base + i, 64);
    float v1 = __shfl(x1, base + i, 64);
    ay += v0 * sWl[i * 16 + l] + v1 * sWl[(16 + i) * 16 + l];
  }
  y[node * 16 + l] = __float2half_rn(ay);
}

__global__ void k_xform16h(const float* __restrict__ hin,
                           const float* __restrict__ Wl,
                           __half* __restrict__ y, int n) {
  __shared__ float sWl[16 * 16];
  int t = threadIdx.x;
  for (int i = t; i < 16 * 16; i += 256) sWl[i] = Wl[i];
  __syncthreads();
  int l = t & 15;
  int base = (t & 63) & ~15;
  int node = (blockIdx.x * 256 + t) >> 4;
  if (node >= n) return;
  float x0 = hin[node * 16 + l];
  float ay = 0.f;
  #pragma unroll
  for (int i = 0; i < 16; ++i) {
    float v0 = __shfl(x0, base + i, 64);
    ay += v0 * sWl[i * 16 + l];
  }
  y[node * 16 + l] = __float2half_rn(ay);
}

// ---------------- aggregate: out = elu(mean_gather(y16) + h@Wr + b) ----------------

template <int DI>
__global__ void k_agg(const __half* __restrict__ y, const float* __restrict__ hin,
                      const float* __restrict__ Wr, const float* __restrict__ bias,
                      const int* __restrict__ rowptr, const int* __restrict__ csr,
                      float* __restrict__ outp, int n) {
  __shared__ __align__(16) float sWr[DI * 16];
  __shared__ float sb[16];
  {
    int tt = threadIdx.x;
    for (int i = tt; i < DI * 16; i += 256) sWr[i] = Wr[i];
    if (tt < 16) sb[tt] = bias[tt];
  }
  __syncthreads();

  int t = blockIdx.x * 256 + threadIdx.x;
  int l = t & 3;
  int node = t >> 2;
  if (node >= n) return;
  int r0 = rowptr[node], r1 = rowptr[node + 1];

  const uint2* __restrict__ yv = reinterpret_cast<const uint2*>(y);

  float a0 = 0.f, a1 = 0.f, a2 = 0.f, a3 = 0.f;
  float b0 = 0.f, b1 = 0.f, b2 = 0.f, b3 = 0.f;
  float c0 = 0.f, c1 = 0.f, c2 = 0.f, c3 = 0.f;
  float d0 = 0.f, d1 = 0.f, d2 = 0.f, d3 = 0.f;
  int k = r0;
  for (; k + 3 < r1; k += 4) {
    int ia = csr[k], ib = csr[k + 1], ic = csr[k + 2], id = csr[k + 3];
    uint2 ra = yv[ia * 4 + l];
    uint2 rb = yv[ib * 4 + l];
    uint2 rc = yv[ic * 4 + l];
    uint2 rd = yv[id * 4 + l];
    float2 fa0 = __half22float2(*reinterpret_cast<const __half2*>(&ra.x));
    float2 fa1 = __half22float2(*reinterpret_cast<const __half2*>(&ra.y));
    float2 fb0 = __half22float2(*reinterpret_cast<const __half2*>(&rb.x));
    float2 fb1 = __half22float2(*reinterpret_cast<const __half2*>(&rb.y));
    float2 fc0 = __half22float2(*reinterpret_cast<const __half2*>(&rc.x));
    float2 fc1 = __half22float2(*reinterpret_cast<const __half2*>(&rc.y));
    float2 fd0 = __half22float2(*reinterpret_cast<const __half2*>(&rd.x));
    float2 fd1 = __half22float2(*reinterpret_cast<const __half2*>(&rd.y));
    a0 += fa0.x; a1 += fa0.y; a2 += fa1.x; a3 += fa1.y;
    b0 += fb0.x; b1 += fb0.y; b2 += fb1.x; b3 += fb1.y;
    c0 += fc0.x; c1 += fc0.y; c2 += fc1.x; c3 += fc1.y;
    d0 += fd0.x; d1 += fd0.y; d2 += fd1.x; d3 += fd1.y;
  }
  for (; k < r1; ++k) {
    int ia = csr[k];
    uint2 ra = yv[ia * 4 + l];
    float2 fa0 = __half22float2(*reinterpret_cast<const __half2*>(&ra.x));
    float2 fa1 = __half22float2(*reinterpret_cast<const __half2*>(&ra.y));
    a0 += fa0.x; a1 += fa0.y; a2 += fa1.x; a3 += fa1.y;
  }
  float s0 = a0 + b0 + c0 + d0;
  float s1 = a1 + b1 + c1 + d1;
  float s2 = a2 + b2 + c2 + d2;
  float s3 = a3 + b3 + c3 + d3;
  float inv = 1.f / fmaxf((float)(r1 - r0), 1.f);

  int cbase = l * 4;
  float4 rr = *reinterpret_cast<const float4*>(&sb[cbase]);
  #pragma unroll
  for (int i = 0; i < DI; ++i) {
    float h = hin[node * DI + i];
    float4 w = *reinterpret_cast<const float4*>(&sWr[i * 16 + cbase]);
    rr.x += h * w.x; rr.y += h * w.y; rr.z += h * w.z; rr.w += h * w.w;
  }

  float ax = s0 * inv + rr.x;
  float ay = s1 * inv + rr.y;
  float az = s2 * inv + rr.z;
  float aw = s3 * inv + rr.w;
  float4 o;
  o.x = ax > 0.f ? ax : (__expf(ax) - 1.f);
  o.y = ay > 0.f ? ay : (__expf(ay) - 1.f);
  o.z = az > 0.f ? az : (__expf(az) - 1.f);
  o.w = aw > 0.f ? aw : (__expf(aw) - 1.f);
  *reinterpret_cast<float4*>(&outp[node * 16 + cbase]) = o;
}

// ---------------- fused 4-layer MLP via MFMA (working, round-10) ----------------

typedef _Float16 f16x4 __attribute__((ext_vector_type(4)));
typedef float f32x4 __attribute__((ext_vector_type(4)));

#define MFMA16(a, b, c) __builtin_amdgcn_mfma_f32_16x16x16f16(a, b, c, 0, 0, 0)
#define CSTRIDE 20  // halves per LDS column slot

__global__ void __launch_bounds__(256) k_mlp(
    const float* __restrict__ xin,
    const float* __restrict__ W0, const float* __restrict__ B0,
    const float* __restrict__ W1, const float* __restrict__ B1,
    const float* __restrict__ W2, const float* __restrict__ B2,
    const float* __restrict__ W3, const float* __restrict__ B3,
    float* __restrict__ out, int n, int nchunks) {
  __shared__ __align__(16) _Float16 hbuf[4][2][64 * CSTRIDE];  // 20.5 KB
  int t = threadIdx.x;
  int w = t >> 6;        // wave in block
  int lane = t & 63;
  int row = lane & 15;   // A-row / D-col index
  int kg = lane >> 4;    // k-group

  f16x4 b0f[4], b1f[4][4], b2f[4][4], b3f[4];
  float bs0[4], bs1v[4], bs2v[4];
  #pragma unroll
  for (int nt = 0; nt < 4; ++nt) {
    #pragma unroll
    for (int j = 0; j < 4; ++j)
      b0f[nt][j] = (_Float16)W0[(kg * 4 + j) * 64 + nt * 16 + row];
    bs0[nt] = B0[nt * 16 + row];
    bs1v[nt] = B1[nt * 16 + row];
    bs2v[nt] = B2[nt * 16 + row];
  }
  #pragma unroll
  for (int ks = 0; ks < 4; ++ks)
    #pragma unroll
    for (int nt = 0; nt < 4; ++nt)
      #pragma unroll
      for (int j = 0; j < 4; ++j) {
        b1f[ks][nt][j] = (_Float16)W1[(ks * 16 + kg * 4 + j) * 64 + nt * 16 + row];
        b2f[ks][nt][j] = (_Float16)W2[(ks * 16 + kg * 4 + j) * 64 + nt * 16 + row];
      }
  #pragma unroll
  for (int ks = 0; ks < 4; ++ks)
    #pragma unroll
    for (int j = 0; j < 4; ++j)
      b3f[ks][j] = (row < 4) ? (_Float16)W3[(ks * 16 + kg * 4 + j) * 4 + row]
                             : (_Float16)0.f;
  float bs3 = (row < 4) ? B3[row] : 0.f;

  _Float16* hb0 = &hbuf[w][0][0];
  _Float16* hb1 = &hbuf[w][1][0];

  for (int c = blockIdx.x; c < nchunks; c += gridDim.x) {
    int nodeBase = c * 64 + w * 16;
    if (nodeBase >= n) continue;

    int nd = nodeBase + row;
    if (nd >= n) nd = n - 1;
    float4 xv = *reinterpret_cast<const float4*>(&xin[nd * 16 + kg * 4]);
    f16x4 a0;
    a0[0] = (_Float16)xv.x; a0[1] = (_Float16)xv.y;
    a0[2] = (_Float16)xv.z; a0[3] = (_Float16)xv.w;
    #pragma unroll
    for (int nt = 0; nt < 4; ++nt) {
      f32x4 acc = {bs0[nt], bs0[nt], bs0[nt], bs0[nt]};
      acc = MFMA16(a0, b0f[nt], acc);
      f16x4 hv;
      #pragma unroll
      for (int i = 0; i < 4; ++i) {
        float v = acc[i];
        v = v > 0.f ? v : (__expf(v) - 1.f);
        hv[i] = (_Float16)v;
      }
      *reinterpret_cast<f16x4*>(&hb0[(nt * 16 + row) * CSTRIDE + kg * 4]) = hv;
    }

    {
      f16x4 a[4];
      #pragma unroll
      for (int ks = 0; ks < 4; ++ks)
        #pragma unroll
        for (int j = 0; j < 4; ++j)
          a[ks][j] = hb0[(ks * 16 + kg * 4 + j) * CSTRIDE + row];
      #pragma unroll
      for (int nt = 0; nt < 4; ++nt) {
        f32x4 acc = {bs1v[nt], bs1v[nt], bs1v[nt], bs1v[nt]};
        #pragma unroll
        for (int ks = 0; ks < 4; ++ks) acc = MFMA16(a[ks], b1f[ks][nt], acc);
        f16x4 hv;
        #pragma unroll
        for (int i = 0; i < 4; ++i) {
          float v = acc[i];
          v = v > 0.f ? v : (__expf(v) - 1.f);
          hv[i] = (_Float16)v;
        }
        *reinterpret_cast<f16x4*>(&hb1[(nt * 16 + row) * CSTRIDE + kg * 4]) = hv;
      }
    }

    {
      f16x4 a[4];
      #pragma unroll
      for (int ks = 0; ks < 4; ++ks)
        #pragma unroll
        for (int j = 0; j < 4; ++j)
          a[ks][j] = hb1[(ks * 16 + kg * 4 + j) * CSTRIDE + row];
      #pragma unroll
      for (int nt = 0; nt < 4; ++nt) {
        f32x4 acc = {bs2v[nt], bs2v[nt], bs2v[nt], bs2v[nt]};
        #pragma unroll
        for (int ks = 0; ks < 4; ++ks) acc = MFMA16(a[ks], b2f[ks][nt], acc);
        f16x4 hv;
        #pragma unroll
        for (int i = 0; i < 4; ++i) {
          float v = acc[i];
          v = v > 0.f ? v : (__expf(v) - 1.f);
          hv[i] = (_Float16)v;
        }
        *reinterpret_cast<f16x4*>(&hb0[(nt * 16 + row) * CSTRIDE + kg * 4]) = hv;
      }
    }

    {
      f16x4 a[4];
      #pragma unroll
      for (int ks = 0; ks < 4; ++ks)
        #pragma unroll
        for (int j = 0; j < 4; ++j)
          a[ks][j] = hb0[(ks * 16 + kg * 4 + j) * CSTRIDE + row];
      f32x4 acc = {bs3, bs3, bs3, bs3};
      #pragma unroll
      for (int ks = 0; ks < 4; ++ks) acc = MFMA16(a[ks], b3f[ks], acc);
      if (row < 4) {
        #pragma unroll
        for (int i = 0; i < 4; ++i) {
          int nd2 = nodeBase + kg * 4 + i;
          if (nd2 < n) out[nd2 * 4 + row] = acc[i];
        }
      }
    }
  }
}

// ---------------- launch ----------------

extern "C" void kernel_launch(void* const* d_in, const int* in_sizes, int n_in,
                              void* d_out, int out_size, void* d_ws, size_t ws_size,
                              hipStream_t stream) {
  const float* x   = (const float*)d_in[0];
  const int*   ei  = (const int*)d_in[1];
  const float* Wl0 = (const float*)d_in[2];
  const float* Wr0 = (const float*)d_in[3];
  const float* bl0 = (const float*)d_in[4];
  const float* Wl1 = (const float*)d_in[5];
  const float* Wr1 = (const float*)d_in[6];
  const float* bl1 = (const float*)d_in[7];
  const float* Wl2 = (const float*)d_in[8];
  const float* Wr2 = (const float*)d_in[9];
  const float* bl2 = (const float*)d_in[10];
  const float* LW0 = (const float*)d_in[11];
  const float* LB0 = (const float*)d_in[12];
  const float* LW1 = (const float*)d_in[13];
  const float* LB1 = (const float*)d_in[14];
  const float* LW2 = (const float*)d_in[15];
  const float* LB2 = (const float*)d_in[16];
  const float* LW3 = (const float*)d_in[17];
  const float* LB3 = (const float*)d_in[18];
  float* out = (float*)d_out;

  const int N_ = in_sizes[0] / 32;   // 100000
  const int E_ = in_sizes[1] / 2;    // 3200000

  const int NB = (N_ + (1 << BSH) - 1) >> BSH;        // 391 buckets
  const int chunk = (E_ + GPART - 1) / GPART;
  const int n2 = NB * GPART;                           // 200192
  const int nb2 = (n2 + 255) / 256;                    // 782 <= 1024

  char* wsp = (char*)d_ws;
  int* cnt    = (int*)wsp;  wsp += sizeof(int) * (size_t)n2;
  int* offT   = (int*)wsp;  wsp += sizeof(int) * (size_t)n2;
  int* part   = (int*)wsp;  wsp += sizeof(int) * 1024;
  int* temp   = (int*)wsp;  wsp += sizeof(int) * (size_t)E_;   // 12.8 MB, dead after k_fine
  int* csr    = (int*)wsp;  wsp += sizeof(int) * (size_t)E_;
  size_t hBytes = sizeof(float) * (size_t)N_ * DCONV;          // 6.4 MB
  float* Ha   = (float*)wsp; wsp += hBytes;
  int* rowptr = (int*)wsp;  wsp += sizeof(int) * (size_t)(N_ + 1);
  // reuse temp: y16 (3.2 MB) + Hb (6.4 MB) <= 12.8 MB
  __half* y16 = (__half*)temp;
  float*  Hb  = (float*)((char*)temp + sizeof(__half) * (size_t)N_ * DCONV);

  // CSR build
  k_hist<<<GPART, 512, 0, stream>>>(ei, E_, NB, chunk, cnt);
  k_block_sums<<<nb2, 256, 0, stream>>>(cnt, n2, part);
  k_scan_part<<<1, 1024, 0, stream>>>(part, nb2);
  k_excl_apply<<<nb2, 256, 0, stream>>>(cnt, n2, part, offT, NB);
  k_scatter<<<GPART, 512, 0, stream>>>(ei, E_, NB, chunk, offT, temp);
  k_fine<<<NB, 512, 0, stream>>>(temp, offT, NB, E_, N_, rowptr, csr);

  int nbX = (N_ * 16 + 255) / 256;   // xform grids
  int nbA = (N_ * 4 + 255) / 256;    // agg grids

  // conv0: x -> Ha
  k_xform32h<<<nbX, 256, 0, stream>>>(x, Wl0, y16, N_);
  k_agg<32><<<nbA, 256, 0, stream>>>(y16, x, Wr0, bl0, rowptr, csr, Ha, N_);
  // conv1: Ha -> Hb
  k_xform16h<<<nbX, 256, 0, stream>>>(Ha, Wl1, y16, N_);
  k_agg<16><<<nbA, 256, 0, stream>>>(y16, Ha, Wr1, bl1, rowptr, csr, Hb, N_);
  // conv2: Hb -> Ha
  k_xform16h<<<nbX, 256, 0, stream>>>(Hb, Wl2, y16, N_);
  k_agg<16><<<nbA, 256, 0, stream>>>(y16, Hb, Wr2, bl2, rowptr, csr, Ha, N_);

  // MLP: MFMA, one wave per 16 nodes, grid-stride
  int nchunks = (N_ + 63) / 64;      // 1563
  int nbM = 512;
  if (nbM > nchunks) nbM = nchunks;
  k_mlp<<<nbM, 256, 0, stream>>>(Ha, LW0, LB0, LW1, LB1, LW2, LB2, LW3, LB3, out, N_, nchunks);
}

// Round 12
// 194.956 us; speedup vs baseline: 1.3438x; 1.1083x over previous
//
#include <hip/hip_runtime.h>
#include <hip/hip_fp16.h>
#include <math.h>

#define DCONV 16
#define BSH 8            // nodes per bucket = 256
#define GPART 512        // partition blocks (parallelism for hist/scatter)
#define GSH 9            // log2(GPART)
#define MAXNB 512
#define SCAP 6912        // >= chunk (6250) : per-block LDS sort capacity
#define FCAP 12288       // >= max bucket size (~8192 + margin)

// ---------------- bucketed CSR build ----------------

__global__ void __launch_bounds__(512) k_hist(const int* __restrict__ ei, int E,
                                              int nb_buckets, int chunk,
                                              int* __restrict__ cnt) {
  __shared__ int hist[MAXNB];
  int g = blockIdx.x;
  for (int i = threadIdx.x; i < nb_buckets; i += 512) hist[i] = 0;
  __syncthreads();
  int e0 = g * chunk, e1 = min(e0 + chunk, E);
  for (int e = e0 + threadIdx.x; e < e1; e += 512)
    atomicAdd(&hist[ei[E + e] >> BSH], 1);
  __syncthreads();
  for (int i = threadIdx.x; i < nb_buckets; i += 512)
    cnt[i * GPART + g] = hist[i];
}

__global__ void k_block_sums(const int* __restrict__ in, int n, int* __restrict__ part) {
  int i = blockIdx.x * 256 + threadIdx.x;
  int v = (i < n) ? in[i] : 0;
  #pragma unroll
  for (int off = 32; off > 0; off >>= 1) v += __shfl_down(v, off, 64);
  __shared__ int ws[4];
  if ((threadIdx.x & 63) == 0) ws[threadIdx.x >> 6] = v;
  __syncthreads();
  if (threadIdx.x == 0) part[blockIdx.x] = ws[0] + ws[1] + ws[2] + ws[3];
}

// single block, 1024 threads; nb <= 1024
__global__ void k_scan_part(int* __restrict__ part, int nb) {
  __shared__ int s[1024];
  int t = threadIdx.x;
  int v = (t < nb) ? part[t] : 0;
  s[t] = v;
  __syncthreads();
  for (int off = 1; off < 1024; off <<= 1) {
    int u = (t >= off) ? s[t - off] : 0;
    __syncthreads();
    s[t] += u;
    __syncthreads();
  }
  if (t < nb) part[t] = s[t] - v;  // exclusive prefix
}

// writes TRANSPOSED offsets: offT[g * nb_buckets + b]
__global__ void k_excl_apply(const int* __restrict__ in, int n, const int* __restrict__ part,
                             int* __restrict__ outT, int nb_buckets) {
  __shared__ int s[256];
  int t = threadIdx.x;
  int i = blockIdx.x * 256 + t;
  int v = (i < n) ? in[i] : 0;
  s[t] = v;
  __syncthreads();
  for (int off = 1; off < 256; off <<= 1) {
    int u = (t >= off) ? s[t - off] : 0;
    __syncthreads();
    s[t] += u;
    __syncthreads();
  }
  if (i < n) {
    int excl = s[t] - v + part[blockIdx.x];
    int b = i >> GSH;
    int g = i & (GPART - 1);
    outT[g * nb_buckets + b] = excl;
  }
}

// LDS batch-sort scatter: sort the block's chunk by bucket in LDS, then write
// bucket-major -> consecutive lanes hit consecutive addresses (coalesced runs)
// instead of 64 random lines per wave-store.
__global__ void __launch_bounds__(512) k_scatter(const int* __restrict__ ei, int E,
                                                 int nb_buckets, int chunk,
                                                 const int* __restrict__ offT,
                                                 int* __restrict__ temp) {
  __shared__ int sh[512];
  __shared__ int lofs[MAXNB];
  __shared__ int lcur[MAXNB];
  __shared__ int gbase[MAXNB];
  __shared__ int sorted[SCAP];
  __shared__ unsigned short sbkt[SCAP];
  int g = blockIdx.x, t = threadIdx.x;
  int e0 = g * chunk, e1 = min(e0 + chunk, E);
  int total = e1 - e0;

  if (total > SCAP) {  // safety fallback: direct scatter
    for (int i = t; i < nb_buckets; i += 512) lcur[i] = offT[(size_t)g * nb_buckets + i];
    __syncthreads();
    for (int e = e0 + t; e < e1; e += 512) {
      int s = ei[e];
      int d = ei[E + e];
      int b = d >> BSH;
      int pos = atomicAdd(&lcur[b], 1);
      temp[pos] = (s << BSH) | (d & ((1 << BSH) - 1));
    }
    return;
  }

  lcur[t] = 0;
  __syncthreads();
  for (int e = e0 + t; e < e1; e += 512)
    atomicAdd(&lcur[ei[E + e] >> BSH], 1);
  __syncthreads();
  int v = (t < nb_buckets) ? lcur[t] : 0;
  sh[t] = v;
  __syncthreads();
  for (int off = 1; off < 512; off <<= 1) {
    int u = (t >= off) ? sh[t - off] : 0;
    __syncthreads();
    sh[t] += u;
    __syncthreads();
  }
  if (t < nb_buckets) {
    int excl = sh[t] - v;
    lofs[t] = excl;
    lcur[t] = excl;
    gbase[t] = offT[(size_t)g * nb_buckets + t];
  }
  __syncthreads();
  for (int e = e0 + t; e < e1; e += 512) {
    int s = ei[e];
    int d = ei[E + e];
    int b = d >> BSH;
    int pos = atomicAdd(&lcur[b], 1);
    sorted[pos] = (s << BSH) | (d & ((1 << BSH) - 1));
    sbkt[pos] = (unsigned short)b;
  }
  __syncthreads();
  for (int i = t; i < total; i += 512) {
    int b = sbkt[i];
    temp[gbase[b] + (i - lofs[b])] = sorted[i];
  }
}

// per-bucket fine sort: scatter into LDS, then stream csr out sequentially.
__global__ void __launch_bounds__(512) k_fine(const int* __restrict__ temp,
                                              const int* __restrict__ offT,
                                              int nb_buckets, int E, int n,
                                              int* __restrict__ rowptr, int* __restrict__ csr) {
  __shared__ int hist[1 << BSH];
  __shared__ int cur[1 << BSH];
  __shared__ int sorted[FCAP];
  int b = blockIdx.x, t = threadIdx.x;
  int lo = offT[b];                                      // g=0 row of offT
  int hi = (b == nb_buckets - 1) ? E : offT[b + 1];
  int cntb = hi - lo;
  if (t < 256) hist[t] = 0;
  __syncthreads();
  for (int e = lo + t; e < hi; e += 512)
    atomicAdd(&hist[temp[e] & 255], 1);
  __syncthreads();
  int v = 0;
  if (t < 256) { v = hist[t]; cur[t] = v; }
  __syncthreads();
  for (int offm = 1; offm < 256; offm <<= 1) {
    int u = (t >= offm && t < 256) ? cur[t - offm] : 0;
    __syncthreads();
    if (t < 256) cur[t] += u;
    __syncthreads();
  }
  bool inlds = (cntb <= FCAP);
  if (t < 256) {
    int excl = cur[t] - v;
    int node = (b << BSH) + t;
    if (node < n) rowptr[node] = lo + excl;
    cur[t] = inlds ? excl : (lo + excl);
  }
  if (b == nb_buckets - 1 && t == 0) rowptr[n] = hi;
  __syncthreads();
  if (inlds) {
    for (int e = lo + t; e < hi; e += 512) {
      int p = temp[e];
      int pos = atomicAdd(&cur[p & 255], 1);
      sorted[pos] = p >> BSH;
    }
    __syncthreads();
    for (int i = t; i < cntb; i += 512) csr[lo + i] = sorted[i];
  } else {
    for (int e = lo + t; e < hi; e += 512) {
      int p = temp[e];
      int pos = atomicAdd(&cur[p & 255], 1);
      csr[pos] = p >> BSH;
    }
  }
}

// ---------------- pre-transform: y = fp16(h @ Wl) ----------------

__global__ void k_xform32h(const float* __restrict__ xin,
                           const float* __restrict__ Wl,
                           __half* __restrict__ y, int n) {
  __shared__ float sWl[32 * 16];
  int t = threadIdx.x;
  for (int i = t; i < 32 * 16; i += 256) sWl[i] = Wl[i];
  __syncthreads();
  int l = t & 15;
  int base = (t & 63) & ~15;
  int node = (blockIdx.x * 256 + t) >> 4;
  if (node >= n) return;
  float x0 = xin[node * 32 + l];
  float x1 = xin[node * 32 + 16 + l];
  float ay = 0.f;
  #pragma unroll
  for (int i = 0; i < 16; ++i) {
    float v0 = __shfl(x0, base + i, 64);
    float v1 = __shfl(x1, base + i, 64);
    ay += v0 * sWl[i * 16 + l] + v1 * sWl[(16 + i) * 16 + l];
  }
  y[node * 16 + l] = __float2half_rn(ay);
}

__global__ void k_xform16h(const float* __restrict__ hin,
                           const float* __restrict__ Wl,
                           __half* __restrict__ y, int n) {
  __shared__ float sWl[16 * 16];
  int t = threadIdx.x;
  for (int i = t; i < 16 * 16; i += 256) sWl[i] = Wl[i];
  __syncthreads();
  int l = t & 15;
  int base = (t & 63) & ~15;
  int node = (blockIdx.x * 256 + t) >> 4;
  if (node >= n) return;
  float x0 = hin[node * 16 + l];
  float ay = 0.f;
  #pragma unroll
  for (int i = 0; i < 16; ++i) {
    float v0 = __shfl(x0, base + i, 64);
    ay += v0 * sWl[i * 16 + l];
  }
  y[node * 16 + l] = __float2half_rn(ay);
}

// ---------------- aggregate: out = elu(mean_gather(y16) + h@Wr + b) ----------------

template <int DI>
__global__ void k_agg(const __half* __restrict__ y, const float* __restrict__ hin,
                      const float* __restrict__ Wr, const float* __restrict__ bias,
                      const int* __restrict__ rowptr, const int* __restrict__ csr,
                      float* __restrict__ outp, int n) {
  __shared__ __align__(16) float sWr[DI * 16];
  __shared__ float sb[16];
  {
    int tt = threadIdx.x;
    for (int i = tt; i < DI * 16; i += 256) sWr[i] = Wr[i];
    if (tt < 16) sb[tt] = bias[tt];
  }
  __syncthreads();

  int t = blockIdx.x * 256 + threadIdx.x;
  int l = t & 3;
  int node = t >> 2;
  if (node >= n) return;
  int r0 = rowptr[node], r1 = rowptr[node + 1];

  const uint2* __restrict__ yv = reinterpret_cast<const uint2*>(y);

  float a0 = 0.f, a1 = 0.f, a2 = 0.f, a3 = 0.f;
  float b0 = 0.f, b1 = 0.f, b2 = 0.f, b3 = 0.f;
  float c0 = 0.f, c1 = 0.f, c2 = 0.f, c3 = 0.f;
  float d0 = 0.f, d1 = 0.f, d2 = 0.f, d3 = 0.f;
  int k = r0;
  for (; k + 3 < r1; k += 4) {
    int ia = csr[k], ib = csr[k + 1], ic = csr[k + 2], id = csr[k + 3];
    uint2 ra = yv[ia * 4 + l];
    uint2 rb = yv[ib * 4 + l];
    uint2 rc = yv[ic * 4 + l];
    uint2 rd = yv[id * 4 + l];
    float2 fa0 = __half22float2(*reinterpret_cast<const __half2*>(&ra.x));
    float2 fa1 = __half22float2(*reinterpret_cast<const __half2*>(&ra.y));
    float2 fb0 = __half22float2(*reinterpret_cast<const __half2*>(&rb.x));
    float2 fb1 = __half22float2(*reinterpret_cast<const __half2*>(&rb.y));
    float2 fc0 = __half22float2(*reinterpret_cast<const __half2*>(&rc.x));
    float2 fc1 = __half22float2(*reinterpret_cast<const __half2*>(&rc.y));
    float2 fd0 = __half22float2(*reinterpret_cast<const __half2*>(&rd.x));
    float2 fd1 = __half22float2(*reinterpret_cast<const __half2*>(&rd.y));
    a0 += fa0.x; a1 += fa0.y; a2 += fa1.x; a3 += fa1.y;
    b0 += fb0.x; b1 += fb0.y; b2 += fb1.x; b3 += fb1.y;
    c0 += fc0.x; c1 += fc0.y; c2 += fc1.x; c3 += fc1.y;
    d0 += fd0.x; d1 += fd0.y; d2 += fd1.x; d3 += fd1.y;
  }
  for (; k < r1; ++k) {
    int ia = csr[k];
    uint2 ra = yv[ia * 4 + l];
    float2 fa0 = __half22float2(*reinterpret_cast<const __half2*>(&ra.x));
    float2 fa1 = __half22float2(*reinterpret_cast<const __half2*>(&ra.y));
    a0 += fa0.x; a1 += fa0.y; a2 += fa1.x; a3 += fa1.y;
  }
  float s0 = a0 + b0 + c0 + d0;
  float s1 = a1 + b1 + c1 + d1;
  float s2 = a2 + b2 + c2 + d2;
  float s3 = a3 + b3 + c3 + d3;
  float inv = 1.f / fmaxf((float)(r1 - r0), 1.f);

  int cbase = l * 4;
  float4 rr = *reinterpret_cast<const float4*>(&sb[cbase]);
  #pragma unroll
  for (int i = 0; i < DI; ++i) {
    float h = hin[node * DI + i];
    float4 w = *reinterpret_cast<const float4*>(&sWr[i * 16 + cbase]);
    rr.x += h * w.x; rr.y += h * w.y; rr.z += h * w.z; rr.w += h * w.w;
  }

  float ax = s0 * inv + rr.x;
  float ay = s1 * inv + rr.y;
  float az = s2 * inv + rr.z;
  float aw = s3 * inv + rr.w;
  float4 o;
  o.x = ax > 0.f ? ax : (__expf(ax) - 1.f);
  o.y = ay > 0.f ? ay : (__expf(ay) - 1.f);
  o.z = az > 0.f ? az : (__expf(az) - 1.f);
  o.w = aw > 0.f ? aw : (__expf(aw) - 1.f);
  *reinterpret_cast<float4*>(&outp[node * 16 + cbase]) = o;
}

// ---------------- fused 4-layer MLP via MFMA (working, round-10) ----------------

typedef _Float16 f16x4 __attribute__((ext_vector_type(4)));
typedef float f32x4 __attribute__((ext_vector_type(4)));

#define MFMA16(a, b, c) __builtin_amdgcn_mfma_f32_16x16x16f16(a, b, c, 0, 0, 0)
#define CSTRIDE 20  // halves per LDS column slot

__global__ void __launch_bounds__(256) k_mlp(
    const float* __restrict__ xin,
    const float* __restrict__ W0, const float* __restrict__ B0,
    const float* __restrict__ W1, const float* __restrict__ B1,
    const float* __restrict__ W2, const float* __restrict__ B2,
    const float* __restrict__ W3, const float* __restrict__ B3,
    float* __restrict__ out, int n, int nchunks) {
  __shared__ __align__(16) _Float16 hbuf[4][2][64 * CSTRIDE];  // 20.5 KB
  int t = threadIdx.x;
  int w = t >> 6;        // wave in block
  int lane = t & 63;
  int row = lane & 15;   // A-row / D-col index
  int kg = lane >> 4;    // k-group

  f16x4 b0f[4], b1f[4][4], b2f[4][4], b3f[4];
  float bs0[4], bs1v[4], bs2v[4];
  #pragma unroll
  for (int nt = 0; nt < 4; ++nt) {
    #pragma unroll
    for (int j = 0; j < 4; ++j)
      b0f[nt][j] = (_Float16)W0[(kg * 4 + j) * 64 + nt * 16 + row];
    bs0[nt] = B0[nt * 16 + row];
    bs1v[nt] = B1[nt * 16 + row];
    bs2v[nt] = B2[nt * 16 + row];
  }
  #pragma unroll
  for (int ks = 0; ks < 4; ++ks)
    #pragma unroll
    for (int nt = 0; nt < 4; ++nt)
      #pragma unroll
      for (int j = 0; j < 4; ++j) {
        b1f[ks][nt][j] = (_Float16)W1[(ks * 16 + kg * 4 + j) * 64 + nt * 16 + row];
        b2f[ks][nt][j] = (_Float16)W2[(ks * 16 + kg * 4 + j) * 64 + nt * 16 + row];
      }
  #pragma unroll
  for (int ks = 0; ks < 4; ++ks)
    #pragma unroll
    for (int j = 0; j < 4; ++j)
      b3f[ks][j] = (row < 4) ? (_Float16)W3[(ks * 16 + kg * 4 + j) * 4 + row]
                             : (_Float16)0.f;
  float bs3 = (row < 4) ? B3[row] : 0.f;

  _Float16* hb0 = &hbuf[w][0][0];
  _Float16* hb1 = &hbuf[w][1][0];

  for (int c = blockIdx.x; c < nchunks; c += gridDim.x) {
    int nodeBase = c * 64 + w * 16;
    if (nodeBase >= n) continue;

    int nd = nodeBase + row;
    if (nd >= n) nd = n - 1;
    float4 xv = *reinterpret_cast<const float4*>(&xin[nd * 16 + kg * 4]);
    f16x4 a0;
    a0[0] = (_Float16)xv.x; a0[1] = (_Float16)xv.y;
    a0[2] = (_Float16)xv.z; a0[3] = (_Float16)xv.w;
    #pragma unroll
    for (int nt = 0; nt < 4; ++nt) {
      f32x4 acc = {bs0[nt], bs0[nt], bs0[nt], bs0[nt]};
      acc = MFMA16(a0, b0f[nt], acc);
      f16x4 hv;
      #pragma unroll
      for (int i = 0; i < 4; ++i) {
        float v = acc[i];
        v = v > 0.f ? v : (__expf(v) - 1.f);
        hv[i] = (_Float16)v;
      }
      *reinterpret_cast<f16x4*>(&hb0[(nt * 16 + row) * CSTRIDE + kg * 4]) = hv;
    }

    {
      f16x4 a[4];
      #pragma unroll
      for (int ks = 0; ks < 4; ++ks)
        #pragma unroll
        for (int j = 0; j < 4; ++j)
          a[ks][j] = hb0[(ks * 16 + kg * 4 + j) * CSTRIDE + row];
      #pragma unroll
      for (int nt = 0; nt < 4; ++nt) {
        f32x4 acc = {bs1v[nt], bs1v[nt], bs1v[nt], bs1v[nt]};
        #pragma unroll
        for (int ks = 0; ks < 4; ++ks) acc = MFMA16(a[ks], b1f[ks][nt], acc);
        f16x4 hv;
        #pragma unroll
        for (int i = 0; i < 4; ++i) {
          float v = acc[i];
          v = v > 0.f ? v : (__expf(v) - 1.f);
          hv[i] = (_Float16)v;
        }
        *reinterpret_cast<f16x4*>(&hb1[(nt * 16 + row) * CSTRIDE + kg * 4]) = hv;
      }
    }

    {
      f16x4 a[4];
      #pragma unroll
      for (int ks = 0; ks < 4; ++ks)
        #pragma unroll
        for (int j = 0; j < 4; ++j)
          a[ks][j] = hb1[(ks * 16 + kg * 4 + j) * CSTRIDE + row];
      #pragma unroll
      for (int nt = 0; nt < 4; ++nt) {
        f32x4 acc = {bs2v[nt], bs2v[nt], bs2v[nt], bs2v[nt]};
        #pragma unroll
        for (int ks = 0; ks < 4; ++ks) acc = MFMA16(a[ks], b2f[ks][nt], acc);
        f16x4 hv;
        #pragma unroll
        for (int i = 0; i < 4; ++i) {
          float v = acc[i];
          v = v > 0.f ? v : (__expf(v) - 1.f);
          hv[i] = (_Float16)v;
        }
        *reinterpret_cast<f16x4*>(&hb0[(nt * 16 + row) * CSTRIDE + kg * 4]) = hv;
      }
    }

    {
      f16x4 a[4];
      #pragma unroll
      for (int ks = 0; ks < 4; ++ks)
        #pragma unroll
        for (int j = 0; j < 4; ++j)
          a[ks][j] = hb0[(ks * 16 + kg * 4 + j) * CSTRIDE + row];
      f32x4 acc = {bs3, bs3, bs3, bs3};
      #pragma unroll
      for (int ks = 0; ks < 4; ++ks) acc = MFMA16(a[ks], b3f[ks], acc);
      if (row < 4) {
        #pragma unroll
        for (int i = 0; i < 4; ++i) {
          int nd2 = nodeBase + kg * 4 + i;
          if (nd2 < n) out[nd2 * 4 + row] = acc[i];
        }
      }
    }
  }
}

// ---------------- launch ----------------

extern "C" void kernel_launch(void* const* d_in, const int* in_sizes, int n_in,
                              void* d_out, int out_size, void* d_ws, size_t ws_size,
                              hipStream_t stream) {
  const float* x   = (const float*)d_in[0];
  const int*   ei  = (const int*)d_in[1];
  const float* Wl0 = (const float*)d_in[2];
  const float* Wr0 = (const float*)d_in[3];
  const float* bl0 = (const float*)d_in[4];
  const float* Wl1 = (const float*)d_in[5];
  const float* Wr1 = (const float*)d_in[6];
  const float* bl1 = (const float*)d_in[7];
  const float* Wl2 = (const float*)d_in[8];
  const float* Wr2 = (const float*)d_in[9];
  const float* bl2 = (const float*)d_in[10];
  const float* LW0 = (const float*)d_in[11];
  const float* LB0 = (const float*)d_in[12];
  const float* LW1 = (const float*)d_in[13];
  const float* LB1 = (const float*)d_in[14];
  const float* LW2 = (const float*)d_in[15];
  const float* LB2 = (const float*)d_in[16];
  const float* LW3 = (const float*)d_in[17];
  const float* LB3 = (const float*)d_in[18];
  float* out = (float*)d_out;

  const int N_ = in_sizes[0] / 32;   // 100000
  const int E_ = in_sizes[1] / 2;    // 3200000

  const int NB = (N_ + (1 << BSH) - 1) >> BSH;        // 391 buckets
  const int chunk = (E_ + GPART - 1) / GPART;          // 6250 <= SCAP
  const int n2 = NB * GPART;                           // 200192
  const int nb2 = (n2 + 255) / 256;                    // 782 <= 1024

  char* wsp = (char*)d_ws;
  int* cnt    = (int*)wsp;  wsp += sizeof(int) * (size_t)n2;
  int* offT   = (int*)wsp;  wsp += sizeof(int) * (size_t)n2;
  int* part   = (int*)wsp;  wsp += sizeof(int) * 1024;
  int* temp   = (int*)wsp;  wsp += sizeof(int) * (size_t)E_;   // 12.8 MB, dead after k_fine
  int* csr    = (int*)wsp;  wsp += sizeof(int) * (size_t)E_;
  size_t hBytes = sizeof(float) * (size_t)N_ * DCONV;          // 6.4 MB
  float* Ha   = (float*)wsp; wsp += hBytes;
  int* rowptr = (int*)wsp;  wsp += sizeof(int) * (size_t)(N_ + 1);
  // reuse temp: y16 (3.2 MB) + Hb (6.4 MB) <= 12.8 MB
  __half* y16 = (__half*)temp;
  float*  Hb  = (float*)((char*)temp + sizeof(__half) * (size_t)N_ * DCONV);

  // CSR build
  k_hist<<<GPART, 512, 0, stream>>>(ei, E_, NB, chunk, cnt);
  k_block_sums<<<nb2, 256, 0, stream>>>(cnt, n2, part);
  k_scan_part<<<1, 1024, 0, stream>>>(part, nb2);
  k_excl_apply<<<nb2, 256, 0, stream>>>(cnt, n2, part, offT, NB);
  k_scatter<<<GPART, 512, 0, stream>>>(ei, E_, NB, chunk, offT, temp);
  k_fine<<<NB, 512, 0, stream>>>(temp, offT, NB, E_, N_, rowptr, csr);

  int nbX = (N_ * 16 + 255) / 256;   // xform grids
  int nbA = (N_ * 4 + 255) / 256;    // agg grids

  // conv0: x -> Ha
  k_xform32h<<<nbX, 256, 0, stream>>>(x, Wl0, y16, N_);
  k_agg<32><<<nbA, 256, 0, stream>>>(y16, x, Wr0, bl0, rowptr, csr, Ha, N_);
  // conv1: Ha -> Hb
  k_xform16h<<<nbX, 256, 0, stream>>>(Ha, Wl1, y16, N_);
  k_agg<16><<<nbA, 256, 0, stream>>>(y16, Ha, Wr1, bl1, rowptr, csr, Hb, N_);
  // conv2: Hb -> Ha
  k_xform16h<<<nbX, 256, 0, stream>>>(Hb, Wl2, y16, N_);
  k_agg<16><<<nbA, 256, 0, stream>>>(y16, Hb, Wr2, bl2, rowptr, csr, Ha, N_);

  // MLP: MFMA, one wave per 16 nodes, grid-stride
  int nchunks = (N_ + 63) / 64;      // 1563
  int nbM = 512;
  if (nbM > nchunks) nbM = nchunks;
  k_mlp<<<nbM, 256, 0, stream>>>(Ha, LW0, LB0, LW1, LB1, LW2, LB2, LW3, LB3, out, N_, nchunks);
}

// Round 13
// 177.278 us; speedup vs baseline: 1.4778x; 1.0997x over previous
//
#include <hip/hip_runtime.h>
#include <hip/hip_fp16.h>
#include <math.h>

#define DCONV 16
#define BSH 8            // nodes per bucket = 256
#define GPART 512        // partition blocks (parallelism for hist/scatter)
#define GSH 9            // log2(GPART)
#define MAXNB 512
#define SCAP 6912        // >= chunk (6250) : per-block LDS sort capacity
#define FCAP 12288       // >= max bucket size (~8192 + margin)

// ---------------- bucketed CSR build ----------------

__global__ void __launch_bounds__(512) k_hist(const int* __restrict__ ei, int E,
                                              int nb_buckets, int chunk,
                                              int* __restrict__ cnt) {
  __shared__ int hist[MAXNB];
  int g = blockIdx.x;
  for (int i = threadIdx.x; i < nb_buckets; i += 512) hist[i] = 0;
  __syncthreads();
  int e0 = g * chunk, e1 = min(e0 + chunk, E);
  for (int e = e0 + threadIdx.x; e < e1; e += 512)
    atomicAdd(&hist[ei[E + e] >> BSH], 1);
  __syncthreads();
  for (int i = threadIdx.x; i < nb_buckets; i += 512)
    cnt[i * GPART + g] = hist[i];
}

__global__ void k_block_sums(const int* __restrict__ in, int n, int* __restrict__ part) {
  int i = blockIdx.x * 256 + threadIdx.x;
  int v = (i < n) ? in[i] : 0;
  #pragma unroll
  for (int off = 32; off > 0; off >>= 1) v += __shfl_down(v, off, 64);
  __shared__ int ws[4];
  if ((threadIdx.x & 63) == 0) ws[threadIdx.x >> 6] = v;
  __syncthreads();
  if (threadIdx.x == 0) part[blockIdx.x] = ws[0] + ws[1] + ws[2] + ws[3];
}

// single block, 1024 threads; nb <= 1024
__global__ void k_scan_part(int* __restrict__ part, int nb) {
  __shared__ int s[1024];
  int t = threadIdx.x;
  int v = (t < nb) ? part[t] : 0;
  s[t] = v;
  __syncthreads();
  for (int off = 1; off < 1024; off <<= 1) {
    int u = (t >= off) ? s[t - off] : 0;
    __syncthreads();
    s[t] += u;
    __syncthreads();
  }
  if (t < nb) part[t] = s[t] - v;  // exclusive prefix
}

// writes TRANSPOSED offsets: offT[g * nb_buckets + b]
__global__ void k_excl_apply(const int* __restrict__ in, int n, const int* __restrict__ part,
                             int* __restrict__ outT, int nb_buckets) {
  __shared__ int s[256];
  int t = threadIdx.x;
  int i = blockIdx.x * 256 + t;
  int v = (i < n) ? in[i] : 0;
  s[t] = v;
  __syncthreads();
  for (int off = 1; off < 256; off <<= 1) {
    int u = (t >= off) ? s[t - off] : 0;
    __syncthreads();
    s[t] += u;
    __syncthreads();
  }
  if (i < n) {
    int excl = s[t] - v + part[blockIdx.x];
    int b = i >> GSH;
    int g = i & (GPART - 1);
    outT[g * nb_buckets + b] = excl;
  }
}

// LDS batch-sort scatter: sort the block's chunk by bucket in LDS, then write
// bucket-major -> coalesced runs instead of 64 random lines per wave-store.
__global__ void __launch_bounds__(512) k_scatter(const int* __restrict__ ei, int E,
                                                 int nb_buckets, int chunk,
                                                 const int* __restrict__ offT,
                                                 int* __restrict__ temp) {
  __shared__ int sh[512];
  __shared__ int lofs[MAXNB];
  __shared__ int lcur[MAXNB];
  __shared__ int gbase[MAXNB];
  __shared__ int sorted[SCAP];
  __shared__ unsigned short sbkt[SCAP];
  int g = blockIdx.x, t = threadIdx.x;
  int e0 = g * chunk, e1 = min(e0 + chunk, E);
  int total = e1 - e0;

  if (total > SCAP) {  // safety fallback: direct scatter
    for (int i = t; i < nb_buckets; i += 512) lcur[i] = offT[(size_t)g * nb_buckets + i];
    __syncthreads();
    for (int e = e0 + t; e < e1; e += 512) {
      int s = ei[e];
      int d = ei[E + e];
      int b = d >> BSH;
      int pos = atomicAdd(&lcur[b], 1);
      temp[pos] = (s << BSH) | (d & ((1 << BSH) - 1));
    }
    return;
  }

  lcur[t] = 0;
  __syncthreads();
  for (int e = e0 + t; e < e1; e += 512)
    atomicAdd(&lcur[ei[E + e] >> BSH], 1);
  __syncthreads();
  int v = (t < nb_buckets) ? lcur[t] : 0;
  sh[t] = v;
  __syncthreads();
  for (int off = 1; off < 512; off <<= 1) {
    int u = (t >= off) ? sh[t - off] : 0;
    __syncthreads();
    sh[t] += u;
    __syncthreads();
  }
  if (t < nb_buckets) {
    int excl = sh[t] - v;
    lofs[t] = excl;
    lcur[t] = excl;
    gbase[t] = offT[(size_t)g * nb_buckets + t];
  }
  __syncthreads();
  for (int e = e0 + t; e < e1; e += 512) {
    int s = ei[e];
    int d = ei[E + e];
    int b = d >> BSH;
    int pos = atomicAdd(&lcur[b], 1);
    sorted[pos] = (s << BSH) | (d & ((1 << BSH) - 1));
    sbkt[pos] = (unsigned short)b;
  }
  __syncthreads();
  for (int i = t; i < total; i += 512) {
    int b = sbkt[i];
    temp[gbase[b] + (i - lofs[b])] = sorted[i];
  }
}

// per-bucket fine sort: scatter into LDS, then stream csr out sequentially.
__global__ void __launch_bounds__(512) k_fine(const int* __restrict__ temp,
                                              const int* __restrict__ offT,
                                              int nb_buckets, int E, int n,
                                              int* __restrict__ rowptr, int* __restrict__ csr) {
  __shared__ int hist[1 << BSH];
  __shared__ int cur[1 << BSH];
  __shared__ int sorted[FCAP];
  int b = blockIdx.x, t = threadIdx.x;
  int lo = offT[b];                                      // g=0 row of offT
  int hi = (b == nb_buckets - 1) ? E : offT[b + 1];
  int cntb = hi - lo;
  if (t < 256) hist[t] = 0;
  __syncthreads();
  for (int e = lo + t; e < hi; e += 512)
    atomicAdd(&hist[temp[e] & 255], 1);
  __syncthreads();
  int v = 0;
  if (t < 256) { v = hist[t]; cur[t] = v; }
  __syncthreads();
  for (int offm = 1; offm < 256; offm <<= 1) {
    int u = (t >= offm && t < 256) ? cur[t - offm] : 0;
    __syncthreads();
    if (t < 256) cur[t] += u;
    __syncthreads();
  }
  bool inlds = (cntb <= FCAP);
  if (t < 256) {
    int excl = cur[t] - v;
    int node = (b << BSH) + t;
    if (node < n) rowptr[node] = lo + excl;
    cur[t] = inlds ? excl : (lo + excl);
  }
  if (b == nb_buckets - 1 && t == 0) rowptr[n] = hi;
  __syncthreads();
  if (inlds) {
    for (int e = lo + t; e < hi; e += 512) {
      int p = temp[e];
      int pos = atomicAdd(&cur[p & 255], 1);
      sorted[pos] = p >> BSH;
    }
    __syncthreads();
    for (int i = t; i < cntb; i += 512) csr[lo + i] = sorted[i];
  } else {
    for (int e = lo + t; e < hi; e += 512) {
      int p = temp[e];
      int pos = atomicAdd(&cur[p & 255], 1);
      csr[pos] = p >> BSH;
    }
  }
}

// ---------------- pre-transform: y = fp16(h @ Wl) ----------------

__global__ void k_xform32h(const float* __restrict__ xin,
                           const float* __restrict__ Wl,
                           __half* __restrict__ y, int n) {
  __shared__ float sWl[32 * 16];
  int t = threadIdx.x;
  for (int i = t; i < 32 * 16; i += 256) sWl[i] = Wl[i];
  __syncthreads();
  int l = t & 15;
  int base = (t & 63) & ~15;
  int node = (blockIdx.x * 256 + t) >> 4;
  if (node >= n) return;
  float x0 = xin[node * 32 + l];
  float x1 = xin[node * 32 + 16 + l];
  float ay = 0.f;
  #pragma unroll
  for (int i = 0; i < 16; ++i) {
    float v0 = __shfl(x0, base + i, 64);
    float v1 = __shfl(x1, base + i, 64);
    ay += v0 * sWl[i * 16 + l] + v1 * sWl[(16 + i) * 16 + l];
  }
  y[node * 16 + l] = __float2half_rn(ay);
}

__global__ void k_xform16h(const float* __restrict__ hin,
                           const float* __restrict__ Wl,
                           __half* __restrict__ y, int n) {
  __shared__ float sWl[16 * 16];
  int t = threadIdx.x;
  for (int i = t; i < 16 * 16; i += 256) sWl[i] = Wl[i];
  __syncthreads();
  int l = t & 15;
  int base = (t & 63) & ~15;
  int node = (blockIdx.x * 256 + t) >> 4;
  if (node >= n) return;
  float x0 = hin[node * 16 + l];
  float ay = 0.f;
  #pragma unroll
  for (int i = 0; i < 16; ++i) {
    float v0 = __shfl(x0, base + i, 64);
    ay += v0 * sWl[i * 16 + l];
  }
  y[node * 16 + l] = __float2half_rn(ay);
}

// ---------------- aggregate: out = elu(mean_gather(y16) + h@Wr + b) ----------------
// 8 lanes/node: lane = (channel-quad l, edge-half h). Each half walks deg/2
// edges (halved latency chain, 2x waves in flight); halves merge via shfl_xor(4).

template <int DI>
__global__ void k_agg(const __half* __restrict__ y, const float* __restrict__ hin,
                      const float* __restrict__ Wr, const float* __restrict__ bias,
                      const int* __restrict__ rowptr, const int* __restrict__ csr,
                      float* __restrict__ outp, int n) {
  __shared__ __align__(16) float sWr[DI * 16];
  __shared__ float sb[16];
  {
    int tt = threadIdx.x;
    for (int i = tt; i < DI * 16; i += 256) sWr[i] = Wr[i];
    if (tt < 16) sb[tt] = bias[tt];
  }
  __syncthreads();

  int t = blockIdx.x * 256 + threadIdx.x;
  int l = t & 3;               // channel quad
  int h = (t >> 2) & 1;        // edge half
  int node = t >> 3;
  if (node >= n) return;
  int r0 = rowptr[node], r1 = rowptr[node + 1];
  int deg = r1 - r0;
  int halfn = (deg + 1) >> 1;
  int ks = r0 + h * halfn;
  int ke = h ? r1 : (r0 + halfn);

  const uint2* __restrict__ yv = reinterpret_cast<const uint2*>(y);

  float a0 = 0.f, a1 = 0.f, a2 = 0.f, a3 = 0.f;
  float b0 = 0.f, b1 = 0.f, b2 = 0.f, b3 = 0.f;
  float c0 = 0.f, c1 = 0.f, c2 = 0.f, c3 = 0.f;
  float d0 = 0.f, d1 = 0.f, d2 = 0.f, d3 = 0.f;
  int k = ks;
  for (; k + 3 < ke; k += 4) {
    int ia = csr[k], ib = csr[k + 1], ic = csr[k + 2], id = csr[k + 3];
    uint2 ra = yv[ia * 4 + l];
    uint2 rb = yv[ib * 4 + l];
    uint2 rc = yv[ic * 4 + l];
    uint2 rd = yv[id * 4 + l];
    float2 fa0 = __half22float2(*reinterpret_cast<const __half2*>(&ra.x));
    float2 fa1 = __half22float2(*reinterpret_cast<const __half2*>(&ra.y));
    float2 fb0 = __half22float2(*reinterpret_cast<const __half2*>(&rb.x));
    float2 fb1 = __half22float2(*reinterpret_cast<const __half2*>(&rb.y));
    float2 fc0 = __half22float2(*reinterpret_cast<const __half2*>(&rc.x));
    float2 fc1 = __half22float2(*reinterpret_cast<const __half2*>(&rc.y));
    float2 fd0 = __half22float2(*reinterpret_cast<const __half2*>(&rd.x));
    float2 fd1 = __half22float2(*reinterpret_cast<const __half2*>(&rd.y));
    a0 += fa0.x; a1 += fa0.y; a2 += fa1.x; a3 += fa1.y;
    b0 += fb0.x; b1 += fb0.y; b2 += fb1.x; b3 += fb1.y;
    c0 += fc0.x; c1 += fc0.y; c2 += fc1.x; c3 += fc1.y;
    d0 += fd0.x; d1 += fd0.y; d2 += fd1.x; d3 += fd1.y;
  }
  for (; k < ke; ++k) {
    int ia = csr[k];
    uint2 ra = yv[ia * 4 + l];
    float2 fa0 = __half22float2(*reinterpret_cast<const __half2*>(&ra.x));
    float2 fa1 = __half22float2(*reinterpret_cast<const __half2*>(&ra.y));
    a0 += fa0.x; a1 += fa0.y; a2 += fa1.x; a3 += fa1.y;
  }
  float s0 = a0 + b0 + c0 + d0;
  float s1 = a1 + b1 + c1 + d1;
  float s2 = a2 + b2 + c2 + d2;
  float s3 = a3 + b3 + c3 + d3;

  // root term: half h covers input channels [h*DI/2, (h+1)*DI/2); bias once (h=0)
  int cbase = l * 4;
  float4 rr;
  if (h == 0) rr = *reinterpret_cast<const float4*>(&sb[cbase]);
  else        rr = make_float4(0.f, 0.f, 0.f, 0.f);
  const int HD = DI / 2;
  #pragma unroll
  for (int i = 0; i < HD; ++i) {
    int ii = h * HD + i;
    float hv = hin[node * DI + ii];
    float4 w = *reinterpret_cast<const float4*>(&sWr[ii * 16 + cbase]);
    rr.x += hv * w.x; rr.y += hv * w.y; rr.z += hv * w.z; rr.w += hv * w.w;
  }

  // merge halves (lane ^ 4)
  s0 += __shfl_xor(s0, 4, 64);
  s1 += __shfl_xor(s1, 4, 64);
  s2 += __shfl_xor(s2, 4, 64);
  s3 += __shfl_xor(s3, 4, 64);
  rr.x += __shfl_xor(rr.x, 4, 64);
  rr.y += __shfl_xor(rr.y, 4, 64);
  rr.z += __shfl_xor(rr.z, 4, 64);
  rr.w += __shfl_xor(rr.w, 4, 64);

  if (h == 0) {
    float inv = 1.f / fmaxf((float)deg, 1.f);
    float ax = s0 * inv + rr.x;
    float ay = s1 * inv + rr.y;
    float az = s2 * inv + rr.z;
    float aw = s3 * inv + rr.w;
    float4 o;
    o.x = ax > 0.f ? ax : (__expf(ax) - 1.f);
    o.y = ay > 0.f ? ay : (__expf(ay) - 1.f);
    o.z = az > 0.f ? az : (__expf(az) - 1.f);
    o.w = aw > 0.f ? aw : (__expf(aw) - 1.f);
    *reinterpret_cast<float4*>(&outp[node * 16 + cbase]) = o;
  }
}

// ---------------- fused 4-layer MLP via MFMA (working, round-10) ----------------

typedef _Float16 f16x4 __attribute__((ext_vector_type(4)));
typedef float f32x4 __attribute__((ext_vector_type(4)));

#define MFMA16(a, b, c) __builtin_amdgcn_mfma_f32_16x16x16f16(a, b, c, 0, 0, 0)
#define CSTRIDE 20  // halves per LDS column slot

__global__ void __launch_bounds__(256) k_mlp(
    const float* __restrict__ xin,
    const float* __restrict__ W0, const float* __restrict__ B0,
    const float* __restrict__ W1, const float* __restrict__ B1,
    const float* __restrict__ W2, const float* __restrict__ B2,
    const float* __restrict__ W3, const float* __restrict__ B3,
    float* __restrict__ out, int n, int nchunks) {
  __shared__ __align__(16) _Float16 hbuf[4][2][64 * CSTRIDE];  // 20.5 KB
  int t = threadIdx.x;
  int w = t >> 6;        // wave in block
  int lane = t & 63;
  int row = lane & 15;   // A-row / D-col index
  int kg = lane >> 4;    // k-group

  f16x4 b0f[4], b1f[4][4], b2f[4][4], b3f[4];
  float bs0[4], bs1v[4], bs2v[4];
  #pragma unroll
  for (int nt = 0; nt < 4; ++nt) {
    #pragma unroll
    for (int j = 0; j < 4; ++j)
      b0f[nt][j] = (_Float16)W0[(kg * 4 + j) * 64 + nt * 16 + row];
    bs0[nt] = B0[nt * 16 + row];
    bs1v[nt] = B1[nt * 16 + row];
    bs2v[nt] = B2[nt * 16 + row];
  }
  #pragma unroll
  for (int ks = 0; ks < 4; ++ks)
    #pragma unroll
    for (int nt = 0; nt < 4; ++nt)
      #pragma unroll
      for (int j = 0; j < 4; ++j) {
        b1f[ks][nt][j] = (_Float16)W1[(ks * 16 + kg * 4 + j) * 64 + nt * 16 + row];
        b2f[ks][nt][j] = (_Float16)W2[(ks * 16 + kg * 4 + j) * 64 + nt * 16 + row];
      }
  #pragma unroll
  for (int ks = 0; ks < 4; ++ks)
    #pragma unroll
    for (int j = 0; j < 4; ++j)
      b3f[ks][j] = (row < 4) ? (_Float16)W3[(ks * 16 + kg * 4 + j) * 4 + row]
                             : (_Float16)0.f;
  float bs3 = (row < 4) ? B3[row] : 0.f;

  _Float16* hb0 = &hbuf[w][0][0];
  _Float16* hb1 = &hbuf[w][1][0];

  for (int c = blockIdx.x; c < nchunks; c += gridDim.x) {
    int nodeBase = c * 64 + w * 16;
    if (nodeBase >= n) continue;

    int nd = nodeBase + row;
    if (nd >= n) nd = n - 1;
    float4 xv = *reinterpret_cast<const float4*>(&xin[nd * 16 + kg * 4]);
    f16x4 a0;
    a0[0] = (_Float16)xv.x; a0[1] = (_Float16)xv.y;
    a0[2] = (_Float16)xv.z; a0[3] = (_Float16)xv.w;
    #pragma unroll
    for (int nt = 0; nt < 4; ++nt) {
      f32x4 acc = {bs0[nt], bs0[nt], bs0[nt], bs0[nt]};
      acc = MFMA16(a0, b0f[nt], acc);
      f16x4 hv;
      #pragma unroll
      for (int i = 0; i < 4; ++i) {
        float v = acc[i];
        v = v > 0.f ? v : (__expf(v) - 1.f);
        hv[i] = (_Float16)v;
      }
      *reinterpret_cast<f16x4*>(&hb0[(nt * 16 + row) * CSTRIDE + kg * 4]) = hv;
    }

    {
      f16x4 a[4];
      #pragma unroll
      for (int ks = 0; ks < 4; ++ks)
        #pragma unroll
        for (int j = 0; j < 4; ++j)
          a[ks][j] = hb0[(ks * 16 + kg * 4 + j) * CSTRIDE + row];
      #pragma unroll
      for (int nt = 0; nt < 4; ++nt) {
        f32x4 acc = {bs1v[nt], bs1v[nt], bs1v[nt], bs1v[nt]};
        #pragma unroll
        for (int ks = 0; ks < 4; ++ks) acc = MFMA16(a[ks], b1f[ks][nt], acc);
        f16x4 hv;
        #pragma unroll
        for (int i = 0; i < 4; ++i) {
          float v = acc[i];
          v = v > 0.f ? v : (__expf(v) - 1.f);
          hv[i] = (_Float16)v;
        }
        *reinterpret_cast<f16x4*>(&hb1[(nt * 16 + row) * CSTRIDE + kg * 4]) = hv;
      }
    }

    {
      f16x4 a[4];
      #pragma unroll
      for (int ks = 0; ks < 4; ++ks)
        #pragma unroll
        for (int j = 0; j < 4; ++j)
          a[ks][j] = hb1[(ks * 16 + kg * 4 + j) * CSTRIDE + row];
      #pragma unroll
      for (int nt = 0; nt < 4; ++nt) {
        f32x4 acc = {bs2v[nt], bs2v[nt], bs2v[nt], bs2v[nt]};
        #pragma unroll
        for (int ks = 0; ks < 4; ++ks) acc = MFMA16(a[ks], b2f[ks][nt], acc);
        f16x4 hv;
        #pragma unroll
        for (int i = 0; i < 4; ++i) {
          float v = acc[i];
          v = v > 0.f ? v : (__expf(v) - 1.f);
          hv[i] = (_Float16)v;
        }
        *reinterpret_cast<f16x4*>(&hb0[(nt * 16 + row) * CSTRIDE + kg * 4]) = hv;
      }
    }

    {
      f16x4 a[4];
      #pragma unroll
      for (int ks = 0; ks < 4; ++ks)
        #pragma unroll
        for (int j = 0; j < 4; ++j)
          a[ks][j] = hb0[(ks * 16 + kg * 4 + j) * CSTRIDE + row];
      f32x4 acc = {bs3, bs3, bs3, bs3};
      #pragma unroll
      for (int ks = 0; ks < 4; ++ks) acc = MFMA16(a[ks], b3f[ks], acc);
      if (row < 4) {
        #pragma unroll
        for (int i = 0; i < 4; ++i) {
          int nd2 = nodeBase + kg * 4 + i;
          if (nd2 < n) out[nd2 * 4 + row] = acc[i];
        }
      }
    }
  }
}

// ---------------- launch ----------------

extern "C" void kernel_launch(void* const* d_in, const int* in_sizes, int n_in,
                              void* d_out, int out_size, void* d_ws, size_t ws_size,
                              hipStream_t stream) {
  const float* x   = (const float*)d_in[0];
  const int*   ei  = (const int*)d_in[1];
  const float* Wl0 = (const float*)d_in[2];
  const float* Wr0 = (const float*)d_in[3];
  const float* bl0 = (const float*)d_in[4];
  const float* Wl1 = (const float*)d_in[5];
  const float* Wr1 = (const float*)d_in[6];
  const float* bl1 = (const float*)d_in[7];
  const float* Wl2 = (const float*)d_in[8];
  const float* Wr2 = (const float*)d_in[9];
  const float* bl2 = (const float*)d_in[10];
  const float* LW0 = (const float*)d_in[11];
  const float* LB0 = (const float*)d_in[12];
  const float* LW1 = (const float*)d_in[13];
  const float* LB1 = (const float*)d_in[14];
  const float* LW2 = (const float*)d_in[15];
  const float* LB2 = (const float*)d_in[16];
  const float* LW3 = (const float*)d_in[17];
  const float* LB3 = (const float*)d_in[18];
  float* out = (float*)d_out;

  const int N_ = in_sizes[0] / 32;   // 100000
  const int E_ = in_sizes[1] / 2;    // 3200000

  const int NB = (N_ + (1 << BSH) - 1) >> BSH;        // 391 buckets
  const int chunk = (E_ + GPART - 1) / GPART;          // 6250 <= SCAP
  const int n2 = NB * GPART;                           // 200192
  const int nb2 = (n2 + 255) / 256;                    // 782 <= 1024

  char* wsp = (char*)d_ws;
  int* cnt    = (int*)wsp;  wsp += sizeof(int) * (size_t)n2;
  int* offT   = (int*)wsp;  wsp += sizeof(int) * (size_t)n2;
  int* part   = (int*)wsp;  wsp += sizeof(int) * 1024;
  int* temp   = (int*)wsp;  wsp += sizeof(int) * (size_t)E_;   // 12.8 MB, dead after k_fine
  int* csr    = (int*)wsp;  wsp += sizeof(int) * (size_t)E_;
  size_t hBytes = sizeof(float) * (size_t)N_ * DCONV;          // 6.4 MB
  float* Ha   = (float*)wsp; wsp += hBytes;
  int* rowptr = (int*)wsp;  wsp += sizeof(int) * (size_t)(N_ + 1);
  // reuse temp: y16 (3.2 MB) + Hb (6.4 MB) <= 12.8 MB
  __half* y16 = (__half*)temp;
  float*  Hb  = (float*)((char*)temp + sizeof(__half) * (size_t)N_ * DCONV);

  // CSR build
  k_hist<<<GPART, 512, 0, stream>>>(ei, E_, NB, chunk, cnt);
  k_block_sums<<<nb2, 256, 0, stream>>>(cnt, n2, part);
  k_scan_part<<<1, 1024, 0, stream>>>(part, nb2);
  k_excl_apply<<<nb2, 256, 0, stream>>>(cnt, n2, part, offT, NB);
  k_scatter<<<GPART, 512, 0, stream>>>(ei, E_, NB, chunk, offT, temp);
  k_fine<<<NB, 512, 0, stream>>>(temp, offT, NB, E_, N_, rowptr, csr);

  int nbX = (N_ * 16 + 255) / 256;   // xform grids
  int nbA = (N_ * 8 + 255) / 256;    // agg grids (8 lanes/node)

  // conv0: x -> Ha
  k_xform32h<<<nbX, 256, 0, stream>>>(x, Wl0, y16, N_);
  k_agg<32><<<nbA, 256, 0, stream>>>(y16, x, Wr0, bl0, rowptr, csr, Ha, N_);
  // conv1: Ha -> Hb
  k_xform16h<<<nbX, 256, 0, stream>>>(Ha, Wl1, y16, N_);
  k_agg<16><<<nbA, 256, 0, stream>>>(y16, Ha, Wr1, bl1, rowptr, csr, Hb, N_);
  // conv2: Hb -> Ha
  k_xform16h<<<nbX, 256, 0, stream>>>(Hb, Wl2, y16, N_);
  k_agg<16><<<nbA, 256, 0, stream>>>(y16, Hb, Wr2, bl2, rowptr, csr, Ha, N_);

  // MLP: MFMA, one wave per 16 nodes, grid-stride
  int nchunks = (N_ + 63) / 64;      // 1563
  int nbM = 512;
  if (nbM > nchunks) nbM = nchunks;
  k_mlp<<<nbM, 256, 0, stream>>>(Ha, LW0, LB0, LW1, LB1, LW2, LB2, LW3, LB3, out, N_, nchunks);
}

// Round 14
// 171.686 us; speedup vs baseline: 1.5260x; 1.0326x over previous
//
#include <hip/hip_runtime.h>
#include <hip/hip_fp16.h>
#include <math.h>

#define DCONV 16
#define BSH 8            // nodes per bucket = 256
#define GPART 512        // partition blocks (parallelism for hist/scatter)
#define GSH 9            // log2(GPART)
#define MAXNB 512
#define SCAP 6912        // >= chunk (6250) : per-block LDS sort capacity
#define FCAP 12288       // >= max bucket size (~8192 + margin)

// ---------------- bucketed CSR build ----------------

__global__ void __launch_bounds__(512) k_hist(const int* __restrict__ ei, int E,
                                              int nb_buckets, int chunk,
                                              int* __restrict__ cnt) {
  __shared__ int hist[MAXNB];
  int g = blockIdx.x;
  for (int i = threadIdx.x; i < nb_buckets; i += 512) hist[i] = 0;
  __syncthreads();
  int e0 = g * chunk, e1 = min(e0 + chunk, E);
  for (int e = e0 + threadIdx.x; e < e1; e += 512)
    atomicAdd(&hist[ei[E + e] >> BSH], 1);
  __syncthreads();
  for (int i = threadIdx.x; i < nb_buckets; i += 512)
    cnt[i * GPART + g] = hist[i];
}

__global__ void k_block_sums(const int* __restrict__ in, int n, int* __restrict__ part) {
  int i = blockIdx.x * 256 + threadIdx.x;
  int v = (i < n) ? in[i] : 0;
  #pragma unroll
  for (int off = 32; off > 0; off >>= 1) v += __shfl_down(v, off, 64);
  __shared__ int ws[4];
  if ((threadIdx.x & 63) == 0) ws[threadIdx.x >> 6] = v;
  __syncthreads();
  if (threadIdx.x == 0) part[blockIdx.x] = ws[0] + ws[1] + ws[2] + ws[3];
}

// single block, 1024 threads; nb <= 1024
__global__ void k_scan_part(int* __restrict__ part, int nb) {
  __shared__ int s[1024];
  int t = threadIdx.x;
  int v = (t < nb) ? part[t] : 0;
  s[t] = v;
  __syncthreads();
  for (int off = 1; off < 1024; off <<= 1) {
    int u = (t >= off) ? s[t - off] : 0;
    __syncthreads();
    s[t] += u;
    __syncthreads();
  }
  if (t < nb) part[t] = s[t] - v;  // exclusive prefix
}

// writes TRANSPOSED offsets: offT[g * nb_buckets + b]
__global__ void k_excl_apply(const int* __restrict__ in, int n, const int* __restrict__ part,
                             int* __restrict__ outT, int nb_buckets) {
  __shared__ int s[256];
  int t = threadIdx.x;
  int i = blockIdx.x * 256 + t;
  int v = (i < n) ? in[i] : 0;
  s[t] = v;
  __syncthreads();
  for (int off = 1; off < 256; off <<= 1) {
    int u = (t >= off) ? s[t - off] : 0;
    __syncthreads();
    s[t] += u;
    __syncthreads();
  }
  if (i < n) {
    int excl = s[t] - v + part[blockIdx.x];
    int b = i >> GSH;
    int g = i & (GPART - 1);
    outT[g * nb_buckets + b] = excl;
  }
}

// LDS batch-sort scatter: sort the block's chunk by bucket in LDS, then write
// bucket-major -> coalesced runs instead of 64 random lines per wave-store.
__global__ void __launch_bounds__(512) k_scatter(const int* __restrict__ ei, int E,
                                                 int nb_buckets, int chunk,
                                                 const int* __restrict__ offT,
                                                 int* __restrict__ temp) {
  __shared__ int sh[512];
  __shared__ int lofs[MAXNB];
  __shared__ int lcur[MAXNB];
  __shared__ int gbase[MAXNB];
  __shared__ int sorted[SCAP];
  __shared__ unsigned short sbkt[SCAP];
  int g = blockIdx.x, t = threadIdx.x;
  int e0 = g * chunk, e1 = min(e0 + chunk, E);
  int total = e1 - e0;

  if (total > SCAP) {  // safety fallback: direct scatter
    for (int i = t; i < nb_buckets; i += 512) lcur[i] = offT[(size_t)g * nb_buckets + i];
    __syncthreads();
    for (int e = e0 + t; e < e1; e += 512) {
      int s = ei[e];
      int d = ei[E + e];
      int b = d >> BSH;
      int pos = atomicAdd(&lcur[b], 1);
      temp[pos] = (s << BSH) | (d & ((1 << BSH) - 1));
    }
    return;
  }

  lcur[t] = 0;
  __syncthreads();
  for (int e = e0 + t; e < e1; e += 512)
    atomicAdd(&lcur[ei[E + e] >> BSH], 1);
  __syncthreads();
  int v = (t < nb_buckets) ? lcur[t] : 0;
  sh[t] = v;
  __syncthreads();
  for (int off = 1; off < 512; off <<= 1) {
    int u = (t >= off) ? sh[t - off] : 0;
    __syncthreads();
    sh[t] += u;
    __syncthreads();
  }
  if (t < nb_buckets) {
    int excl = sh[t] - v;
    lofs[t] = excl;
    lcur[t] = excl;
    gbase[t] = offT[(size_t)g * nb_buckets + t];
  }
  __syncthreads();
  for (int e = e0 + t; e < e1; e += 512) {
    int s = ei[e];
    int d = ei[E + e];
    int b = d >> BSH;
    int pos = atomicAdd(&lcur[b], 1);
    sorted[pos] = (s << BSH) | (d & ((1 << BSH) - 1));
    sbkt[pos] = (unsigned short)b;
  }
  __syncthreads();
  for (int i = t; i < total; i += 512) {
    int b = sbkt[i];
    temp[gbase[b] + (i - lofs[b])] = sorted[i];
  }
}

// per-bucket fine sort: scatter into LDS, then stream csr out sequentially.
__global__ void __launch_bounds__(512) k_fine(const int* __restrict__ temp,
                                              const int* __restrict__ offT,
                                              int nb_buckets, int E, int n,
                                              int* __restrict__ rowptr, int* __restrict__ csr) {
  __shared__ int hist[1 << BSH];
  __shared__ int cur[1 << BSH];
  __shared__ int sorted[FCAP];
  int b = blockIdx.x, t = threadIdx.x;
  int lo = offT[b];                                      // g=0 row of offT
  int hi = (b == nb_buckets - 1) ? E : offT[b + 1];
  int cntb = hi - lo;
  if (t < 256) hist[t] = 0;
  __syncthreads();
  for (int e = lo + t; e < hi; e += 512)
    atomicAdd(&hist[temp[e] & 255], 1);
  __syncthreads();
  int v = 0;
  if (t < 256) { v = hist[t]; cur[t] = v; }
  __syncthreads();
  for (int offm = 1; offm < 256; offm <<= 1) {
    int u = (t >= offm && t < 256) ? cur[t - offm] : 0;
    __syncthreads();
    if (t < 256) cur[t] += u;
    __syncthreads();
  }
  bool inlds = (cntb <= FCAP);
  if (t < 256) {
    int excl = cur[t] - v;
    int node = (b << BSH) + t;
    if (node < n) rowptr[node] = lo + excl;
    cur[t] = inlds ? excl : (lo + excl);
  }
  if (b == nb_buckets - 1 && t == 0) rowptr[n] = hi;
  __syncthreads();
  if (inlds) {
    for (int e = lo + t; e < hi; e += 512) {
      int p = temp[e];
      int pos = atomicAdd(&cur[p & 255], 1);
      sorted[pos] = p >> BSH;
    }
    __syncthreads();
    for (int i = t; i < cntb; i += 512) csr[lo + i] = sorted[i];
  } else {
    for (int e = lo + t; e < hi; e += 512) {
      int p = temp[e];
      int pos = atomicAdd(&cur[p & 255], 1);
      csr[pos] = p >> BSH;
    }
  }
}

// ---------------- pre-transform: y = fp16(x @ Wl0) (layer 0 only) ----------------

__global__ void k_xform32h(const float* __restrict__ xin,
                           const float* __restrict__ Wl,
                           __half* __restrict__ y, int n) {
  __shared__ float sWl[32 * 16];
  int t = threadIdx.x;
  for (int i = t; i < 32 * 16; i += 256) sWl[i] = Wl[i];
  __syncthreads();
  int l = t & 15;
  int base = (t & 63) & ~15;
  int node = (blockIdx.x * 256 + t) >> 4;
  if (node >= n) return;
  float x0 = xin[node * 32 + l];
  float x1 = xin[node * 32 + 16 + l];
  float ay = 0.f;
  #pragma unroll
  for (int i = 0; i < 16; ++i) {
    float v0 = __shfl(x0, base + i, 64);
    float v1 = __shfl(x1, base + i, 64);
    ay += v0 * sWl[i * 16 + l] + v1 * sWl[(16 + i) * 16 + l];
  }
  y[node * 16 + l] = __float2half_rn(ay);
}

// ---------------- aggregate: h_out = elu(mean_gather(y16) + h@Wr + b), optionally
// fused with the NEXT layer's xform: ynext = fp16(h_out @ Wlnext).
// 16 lanes/node: lane = (channel-quad l, edge-quarter q). Quarters merge via
// shfl_xor(4) + shfl_xor(8); after the butterfly ALL 16 lanes hold the full row,
// so the fused epilogue computes one y-channel per lane via broadcast shuffles.

template <int DI, bool FUSE>
__global__ void k_agg(const __half* __restrict__ y, const float* __restrict__ hin,
                      const float* __restrict__ Wr, const float* __restrict__ bias,
                      const float* __restrict__ Wlnext,
                      const int* __restrict__ rowptr, const int* __restrict__ csr,
                      float* __restrict__ outp, __half* __restrict__ ynext, int n) {
  __shared__ __align__(16) float sWr[DI * 16];
  __shared__ float sb[16];
  __shared__ float sWl[16 * 16];
  {
    int tt = threadIdx.x;
    for (int i = tt; i < DI * 16; i += 256) sWr[i] = Wr[i];
    if (tt < 16) sb[tt] = bias[tt];
    if (FUSE) sWl[tt] = Wlnext[tt];
  }
  __syncthreads();

  int t = blockIdx.x * 256 + threadIdx.x;
  int l = t & 3;               // channel quad
  int q = (t >> 2) & 3;        // edge quarter
  int node = t >> 4;
  if (node >= n) return;
  int r0 = rowptr[node], r1 = rowptr[node + 1];
  int deg = r1 - r0;
  int quarter = (deg + 3) >> 2;
  int ks = r0 + q * quarter;
  int ke = min(ks + quarter, r1);

  const uint2* __restrict__ yv = reinterpret_cast<const uint2*>(y);

  float a0 = 0.f, a1 = 0.f, a2 = 0.f, a3 = 0.f;
  float b0 = 0.f, b1 = 0.f, b2 = 0.f, b3 = 0.f;
  float c0 = 0.f, c1 = 0.f, c2 = 0.f, c3 = 0.f;
  float d0 = 0.f, d1 = 0.f, d2 = 0.f, d3 = 0.f;
  int k = ks;
  for (; k + 3 < ke; k += 4) {
    int ia = csr[k], ib = csr[k + 1], ic = csr[k + 2], id = csr[k + 3];
    uint2 ra = yv[ia * 4 + l];
    uint2 rb = yv[ib * 4 + l];
    uint2 rc = yv[ic * 4 + l];
    uint2 rd = yv[id * 4 + l];
    float2 fa0 = __half22float2(*reinterpret_cast<const __half2*>(&ra.x));
    float2 fa1 = __half22float2(*reinterpret_cast<const __half2*>(&ra.y));
    float2 fb0 = __half22float2(*reinterpret_cast<const __half2*>(&rb.x));
    float2 fb1 = __half22float2(*reinterpret_cast<const __half2*>(&rb.y));
    float2 fc0 = __half22float2(*reinterpret_cast<const __half2*>(&rc.x));
    float2 fc1 = __half22float2(*reinterpret_cast<const __half2*>(&rc.y));
    float2 fd0 = __half22float2(*reinterpret_cast<const __half2*>(&rd.x));
    float2 fd1 = __half22float2(*reinterpret_cast<const __half2*>(&rd.y));
    a0 += fa0.x; a1 += fa0.y; a2 += fa1.x; a3 += fa1.y;
    b0 += fb0.x; b1 += fb0.y; b2 += fb1.x; b3 += fb1.y;
    c0 += fc0.x; c1 += fc0.y; c2 += fc1.x; c3 += fc1.y;
    d0 += fd0.x; d1 += fd0.y; d2 += fd1.x; d3 += fd1.y;
  }
  for (; k < ke; ++k) {
    int ia = csr[k];
    uint2 ra = yv[ia * 4 + l];
    float2 fa0 = __half22float2(*reinterpret_cast<const __half2*>(&ra.x));
    float2 fa1 = __half22float2(*reinterpret_cast<const __half2*>(&ra.y));
    a0 += fa0.x; a1 += fa0.y; a2 += fa1.x; a3 += fa1.y;
  }
  float s0 = (a0 + b0) + (c0 + d0);
  float s1 = (a1 + b1) + (c1 + d1);
  float s2 = (a2 + b2) + (c2 + d2);
  float s3 = (a3 + b3) + (c3 + d3);

  // root term: quarter q covers input channels [q*DI/4, (q+1)*DI/4); bias once (q=0)
  int cbase = l * 4;
  float4 rr;
  if (q == 0) rr = *reinterpret_cast<const float4*>(&sb[cbase]);
  else        rr = make_float4(0.f, 0.f, 0.f, 0.f);
  const int QD = DI / 4;
  #pragma unroll
  for (int i = 0; i < QD; ++i) {
    int ii = q * QD + i;
    float hv = hin[node * DI + ii];
    float4 w = *reinterpret_cast<const float4*>(&sWr[ii * 16 + cbase]);
    rr.x += hv * w.x; rr.y += hv * w.y; rr.z += hv * w.z; rr.w += hv * w.w;
  }

  // butterfly merge across quarters (lanes differ in bits 2,3) -> all lanes hold totals
  #pragma unroll
  for (int m = 4; m <= 8; m <<= 1) {
    s0 += __shfl_xor(s0, m, 64);
    s1 += __shfl_xor(s1, m, 64);
    s2 += __shfl_xor(s2, m, 64);
    s3 += __shfl_xor(s3, m, 64);
    rr.x += __shfl_xor(rr.x, m, 64);
    rr.y += __shfl_xor(rr.y, m, 64);
    rr.z += __shfl_xor(rr.z, m, 64);
    rr.w += __shfl_xor(rr.w, m, 64);
  }

  float inv = 1.f / fmaxf((float)deg, 1.f);
  float ax = s0 * inv + rr.x;
  float ay = s1 * inv + rr.y;
  float az = s2 * inv + rr.z;
  float aw = s3 * inv + rr.w;
  float4 o;
  o.x = ax > 0.f ? ax : (__expf(ax) - 1.f);
  o.y = ay > 0.f ? ay : (__expf(ay) - 1.f);
  o.z = az > 0.f ? az : (__expf(az) - 1.f);
  o.w = aw > 0.f ? aw : (__expf(aw) - 1.f);
  if (q == 0) {
    *reinterpret_cast<float4*>(&outp[node * 16 + cbase]) = o;
  }

  if (FUSE) {
    // ynext[c] = sum_i o_row[i] * Wlnext[i][c]; lane computes c = t&15.
    int c = t & 15;
    int grpbase = (threadIdx.x & 63) & ~15;
    float acc = 0.f;
    #pragma unroll
    for (int i = 0; i < 16; ++i) {
      int src = grpbase + (i >> 2);
      float hv;
      switch (i & 3) {
        case 0: hv = __shfl(o.x, src, 64); break;
        case 1: hv = __shfl(o.y, src, 64); break;
        case 2: hv = __shfl(o.z, src, 64); break;
        default: hv = __shfl(o.w, src, 64); break;
      }
      acc += hv * sWl[i * 16 + c];
    }
    ynext[node * 16 + c] = __float2half_rn(acc);
  }
}

// ---------------- fused 4-layer MLP via MFMA (working, round-10) ----------------

typedef _Float16 f16x4 __attribute__((ext_vector_type(4)));
typedef float f32x4 __attribute__((ext_vector_type(4)));

#define MFMA16(a, b, c) __builtin_amdgcn_mfma_f32_16x16x16f16(a, b, c, 0, 0, 0)
#define CSTRIDE 20  // halves per LDS column slot

__global__ void __launch_bounds__(256) k_mlp(
    const float* __restrict__ xin,
    const float* __restrict__ W0, const float* __restrict__ B0,
    const float* __restrict__ W1, const float* __restrict__ B1,
    const float* __restrict__ W2, const float* __restrict__ B2,
    const float* __restrict__ W3, const float* __restrict__ B3,
    float* __restrict__ out, int n, int nchunks) {
  __shared__ __align__(16) _Float16 hbuf[4][2][64 * CSTRIDE];  // 20.5 KB
  int t = threadIdx.x;
  int w = t >> 6;        // wave in block
  int lane = t & 63;
  int row = lane & 15;   // A-row / D-col index
  int kg = lane >> 4;    // k-group

  f16x4 b0f[4], b1f[4][4], b2f[4][4], b3f[4];
  float bs0[4], bs1v[4], bs2v[4];
  #pragma unroll
  for (int nt = 0; nt < 4; ++nt) {
    #pragma unroll
    for (int j = 0; j < 4; ++j)
      b0f[nt][j] = (_Float16)W0[(kg * 4 + j) * 64 + nt * 16 + row];
    bs0[nt] = B0[nt * 16 + row];
    bs1v[nt] = B1[nt * 16 + row];
    bs2v[nt] = B2[nt * 16 + row];
  }
  #pragma unroll
  for (int ks = 0; ks < 4; ++ks)
    #pragma unroll
    for (int nt = 0; nt < 4; ++nt)
      #pragma unroll
      for (int j = 0; j < 4; ++j) {
        b1f[ks][nt][j] = (_Float16)W1[(ks * 16 + kg * 4 + j) * 64 + nt * 16 + row];
        b2f[ks][nt][j] = (_Float16)W2[(ks * 16 + kg * 4 + j) * 64 + nt * 16 + row];
      }
  #pragma unroll
  for (int ks = 0; ks < 4; ++ks)
    #pragma unroll
    for (int j = 0; j < 4; ++j)
      b3f[ks][j] = (row < 4) ? (_Float16)W3[(ks * 16 + kg * 4 + j) * 4 + row]
                             : (_Float16)0.f;
  float bs3 = (row < 4) ? B3[row] : 0.f;

  _Float16* hb0 = &hbuf[w][0][0];
  _Float16* hb1 = &hbuf[w][1][0];

  for (int c = blockIdx.x; c < nchunks; c += gridDim.x) {
    int nodeBase = c * 64 + w * 16;
    if (nodeBase >= n) continue;

    int nd = nodeBase + row;
    if (nd >= n) nd = n - 1;
    float4 xv = *reinterpret_cast<const float4*>(&xin[nd * 16 + kg * 4]);
    f16x4 a0;
    a0[0] = (_Float16)xv.x; a0[1] = (_Float16)xv.y;
    a0[2] = (_Float16)xv.z; a0[3] = (_Float16)xv.w;
    #pragma unroll
    for (int nt = 0; nt < 4; ++nt) {
      f32x4 acc = {bs0[nt], bs0[nt], bs0[nt], bs0[nt]};
      acc = MFMA16(a0, b0f[nt], acc);
      f16x4 hv;
      #pragma unroll
      for (int i = 0; i < 4; ++i) {
        float v = acc[i];
        v = v > 0.f ? v : (__expf(v) - 1.f);
        hv[i] = (_Float16)v;
      }
      *reinterpret_cast<f16x4*>(&hb0[(nt * 16 + row) * CSTRIDE + kg * 4]) = hv;
    }

    {
      f16x4 a[4];
      #pragma unroll
      for (int ks = 0; ks < 4; ++ks)
        #pragma unroll
        for (int j = 0; j < 4; ++j)
          a[ks][j] = hb0[(ks * 16 + kg * 4 + j) * CSTRIDE + row];
      #pragma unroll
      for (int nt = 0; nt < 4; ++nt) {
        f32x4 acc = {bs1v[nt], bs1v[nt], bs1v[nt], bs1v[nt]};
        #pragma unroll
        for (int ks = 0; ks < 4; ++ks) acc = MFMA16(a[ks], b1f[ks][nt], acc);
        f16x4 hv;
        #pragma unroll
        for (int i = 0; i < 4; ++i) {
          float v = acc[i];
          v = v > 0.f ? v : (__expf(v) - 1.f);
          hv[i] = (_Float16)v;
        }
        *reinterpret_cast<f16x4*>(&hb1[(nt * 16 + row) * CSTRIDE + kg * 4]) = hv;
      }
    }

    {
      f16x4 a[4];
      #pragma unroll
      for (int ks = 0; ks < 4; ++ks)
        #pragma unroll
        for (int j = 0; j < 4; ++j)
          a[ks][j] = hb1[(ks * 16 + kg * 4 + j) * CSTRIDE + row];
      #pragma unroll
      for (int nt = 0; nt < 4; ++nt) {
        f32x4 acc = {bs2v[nt], bs2v[nt], bs2v[nt], bs2v[nt]};
        #pragma unroll
        for (int ks = 0; ks < 4; ++ks) acc = MFMA16(a[ks], b2f[ks][nt], acc);
        f16x4 hv;
        #pragma unroll
        for (int i = 0; i < 4; ++i) {
          float v = acc[i];
          v = v > 0.f ? v : (__expf(v) - 1.f);
          hv[i] = (_Float16)v;
        }
        *reinterpret_cast<f16x4*>(&hb0[(nt * 16 + row) * CSTRIDE + kg * 4]) = hv;
      }
    }

    {
      f16x4 a[4];
      #pragma unroll
      for (int ks = 0; ks < 4; ++ks)
        #pragma unroll
        for (int j = 0; j < 4; ++j)
          a[ks][j] = hb0[(ks * 16 + kg * 4 + j) * CSTRIDE + row];
      f32x4 acc = {bs3, bs3, bs3, bs3};
      #pragma unroll
      for (int ks = 0; ks < 4; ++ks) acc = MFMA16(a[ks], b3f[ks], acc);
      if (row < 4) {
        #pragma unroll
        for (int i = 0; i < 4; ++i) {
          int nd2 = nodeBase + kg * 4 + i;
          if (nd2 < n) out[nd2 * 4 + row] = acc[i];
        }
      }
    }
  }
}

// ---------------- launch ----------------

extern "C" void kernel_launch(void* const* d_in, const int* in_sizes, int n_in,
                              void* d_out, int out_size, void* d_ws, size_t ws_size,
                              hipStream_t stream) {
  const float* x   = (const float*)d_in[0];
  const int*   ei  = (const int*)d_in[1];
  const float* Wl0 = (const float*)d_in[2];
  const float* Wr0 = (const float*)d_in[3];
  const float* bl0 = (const float*)d_in[4];
  const float* Wl1 = (const float*)d_in[5];
  const float* Wr1 = (const float*)d_in[6];
  const float* bl1 = (const float*)d_in[7];
  const float* Wl2 = (const float*)d_in[8];
  const float* Wr2 = (const float*)d_in[9];
  const float* bl2 = (const float*)d_in[10];
  const float* LW0 = (const float*)d_in[11];
  const float* LB0 = (const float*)d_in[12];
  const float* LW1 = (const float*)d_in[13];
  const float* LB1 = (const float*)d_in[14];
  const float* LW2 = (const float*)d_in[15];
  const float* LB2 = (const float*)d_in[16];
  const float* LW3 = (const float*)d_in[17];
  const float* LB3 = (const float*)d_in[18];
  float* out = (float*)d_out;

  const int N_ = in_sizes[0] / 32;   // 100000
  const int E_ = in_sizes[1] / 2;    // 3200000

  const int NB = (N_ + (1 << BSH) - 1) >> BSH;        // 391 buckets
  const int chunk = (E_ + GPART - 1) / GPART;          // 6250 <= SCAP
  const int n2 = NB * GPART;                           // 200192
  const int nb2 = (n2 + 255) / 256;                    // 782 <= 1024

  char* wsp = (char*)d_ws;
  int* cnt    = (int*)wsp;  wsp += sizeof(int) * (size_t)n2;
  int* offT   = (int*)wsp;  wsp += sizeof(int) * (size_t)n2;
  int* part   = (int*)wsp;  wsp += sizeof(int) * 1024;
  int* temp   = (int*)wsp;  wsp += sizeof(int) * (size_t)E_;   // 12.8 MB, dead after k_fine
  int* csr    = (int*)wsp;  wsp += sizeof(int) * (size_t)E_;
  size_t hBytes = sizeof(float) * (size_t)N_ * DCONV;          // 6.4 MB
  float* Ha   = (float*)wsp; wsp += hBytes;
  int* rowptr = (int*)wsp;  wsp += sizeof(int) * (size_t)(N_ + 1);
  // reuse temp after k_fine: y16a (3.2 MB) + y16b (3.2 MB) + Hb (6.4 MB) = 12.8 MB
  size_t yBytes = sizeof(__half) * (size_t)N_ * DCONV;         // 3.2 MB
  __half* y16a = (__half*)temp;
  __half* y16b = (__half*)((char*)temp + yBytes);
  float*  Hb   = (float*)((char*)temp + 2 * yBytes);

  // CSR build
  k_hist<<<GPART, 512, 0, stream>>>(ei, E_, NB, chunk, cnt);
  k_block_sums<<<nb2, 256, 0, stream>>>(cnt, n2, part);
  k_scan_part<<<1, 1024, 0, stream>>>(part, nb2);
  k_excl_apply<<<nb2, 256, 0, stream>>>(cnt, n2, part, offT, NB);
  k_scatter<<<GPART, 512, 0, stream>>>(ei, E_, NB, chunk, offT, temp);
  k_fine<<<NB, 512, 0, stream>>>(temp, offT, NB, E_, N_, rowptr, csr);

  int nbX = (N_ * 16 + 255) / 256;   // xform grid
  int nbA = (N_ * 16 + 255) / 256;   // agg grid (16 lanes/node)

  // conv0: x -> Ha ; fused xform -> y16b (= Ha @ Wl1)
  k_xform32h<<<nbX, 256, 0, stream>>>(x, Wl0, y16a, N_);
  k_agg<32, true><<<nbA, 256, 0, stream>>>(y16a, x, Wr0, bl0, Wl1, rowptr, csr, Ha, y16b, N_);
  // conv1: Ha -> Hb ; fused xform -> y16a (= Hb @ Wl2)
  k_agg<16, true><<<nbA, 256, 0, stream>>>(y16b, Ha, Wr1, bl1, Wl2, rowptr, csr, Hb, y16a, N_);
  // conv2: Hb -> Ha (no fusion)
  k_agg<16, false><<<nbA, 256, 0, stream>>>(y16a, Hb, Wr2, bl2, nullptr, rowptr, csr, Ha, nullptr, N_);

  // MLP: MFMA, one wave per 16 nodes, grid-stride
  int nchunks = (N_ + 63) / 64;      // 1563
  int nbM = 512;
  if (nbM > nchunks) nbM = nchunks;
  k_mlp<<<nbM, 256, 0, stream>>>(Ha, LW0, LB0, LW1, LB1, LW2, LB2, LW3, LB3, out, N_, nchunks);
}